// Round 2
// baseline (5058.549 us; speedup 1.0000x reference)
//
#include <hip/hip_runtime.h>
#include <stdint.h>

typedef unsigned int uint32;
typedef unsigned long long u64;

#define BATCH 8
#define LDIM 4096
#define CDIM 128
#define TILE 128

typedef __attribute__((ext_vector_type(4))) int i32x4;
typedef __attribute__((ext_vector_type(16))) int i32x16;

// ---- workspace layout (bytes) ----
#define DIG1_OFF    0ull          /* i8 digits f1: [4 planes][4 kc][8*4096][32] = 16 MB */
#define DIG2_OFF    16777216ull   /* i8 digits f2 */
#define ROWPART_OFF 33554432ull   /* float2 [8][4096][32] = 8 MB */
#define COLPART_OFF 41943040ull
#define LSER_OFF    50331648ull   /* double [8][4096] */
#define LSEC_OFF    50593792ull
#define RPACK_OFF   50855936ull   /* u64 [8][4096] */
#define CPACK_OFF   51118080ull
#define WS_NEEDED   51380224ull

__device__ __forceinline__ uint32 fkey(float f) {
    uint32 u = __float_as_uint(f);
    return (u & 0x80000000u) ? ~u : (u | 0x80000000u);
}
__device__ __forceinline__ float keyf(uint32 k) {
    uint32 u = (k & 0x80000000u) ? (k ^ 0x80000000u) : ~k;
    return __uint_as_float(u);
}
__device__ __forceinline__ i32x16 mfma_i8(i32x4 a, i32x4 b, i32x16 c) {
    return __builtin_amdgcn_mfma_i32_32x32x32_i8(a, b, c, 0, 0, 0);
}

__global__ void fill_sentinel(float* out, int nelem) {
    int i = blockIdx.x * 256 + threadIdx.x;
    if (i < nelem) out[i] = 12345.0f;
}

__global__ void init_packs(u64* __restrict__ rowpack, u64* __restrict__ colpack) {
    int idx = blockIdx.x * 256 + threadIdx.x;
    if (idx < BATCH * LDIM) { rowpack[idx] = 0ull; colpack[idx] = 0ull; }
}

// Quantize fp32 -> exact 4x base-128 signed digits of round(x * 2^25).
__global__ __launch_bounds__(256) void quant_kernel(const float* __restrict__ f1,
                                                    const float* __restrict__ f2,
                                                    char* __restrict__ dig)
{
    int u = blockIdx.x * 256 + threadIdx.x;   // 0 .. 2*1048576-1 (float4 quads)
    int inp = u >> 20;
    int e = u & 1048575;
    int nl = e >> 5;          // n*4096 + l
    int q32 = e & 31;         // quad within row of 128
    const float* src = inp ? f2 : f1;
    char* dst = dig + (inp ? DIG2_OFF : DIG1_OFF);
    float4 v = ((const float4*)src)[(size_t)e];
    int kc = q32 >> 3;
    int k32 = (q32 & 7) * 4;
    float xs[4] = {v.x, v.y, v.z, v.w};
    int ds[4][4];
#pragma unroll
    for (int j = 0; j < 4; j++) {
        int q = __float2int_rn(xs[j] * 33554432.0f);     // x * 2^25
        int d0 = (q + (1 << 20)) >> 21; q -= d0 << 21;
        int d1 = (q + (1 << 13)) >> 14; q -= d1 << 14;
        int d2 = (q + (1 << 6)) >> 7;   q -= d2 << 7;
        ds[0][j] = d0; ds[1][j] = d1; ds[2][j] = d2; ds[3][j] = q;
    }
#pragma unroll
    for (int p = 0; p < 4; p++) {
        uint32 w = (uint32)(ds[p][0] & 255) | ((uint32)(ds[p][1] & 255) << 8)
                 | ((uint32)(ds[p][2] & 255) << 16) | ((uint32)(ds[p][3] & 255) << 24);
        *(uint32*)(dst + ((size_t)(p * 4 + kc) * 32768 + nl) * 32 + k32) = w;
    }
}

// PASS 1: exact i8-digit GEMM -> per-tile (max, sumexp) row/col partials.
// PASS 2: recompute -> packed argmax keys of g = 2*lambda - lse_r - lse_c.
// 8 waves: 4 regions (2x2 of 64x64) x 2 bank-groups (bg0: s={0,3}, bg1: s={1,2}).
template <int PASS>
__global__ __launch_bounds__(512, 2) void gemm_kernel(
    const char* __restrict__ dig,
    float2* __restrict__ rowpart, float2* __restrict__ colpart,
    const double* __restrict__ lse_row, const double* __restrict__ lse_col,
    u64* __restrict__ rowpack, u64* __restrict__ colpack)
{
    const int tileN = blockIdx.x, tileM = blockIdx.y, n = blockIdx.z;
    const int t = threadIdx.x;
    const int lane = t & 63, wave = t >> 6;
    const int bg = wave >> 2;
    const int regR = (wave >> 1) & 1, regC = wave & 1;
    const int l31 = lane & 31, kg = lane >> 5;

    __shared__ __align__(16) char lds[41984];
    // [0,32768): stage A(16KB)+B(16KB), reused as exchange (32KB)
    double* epiRM = (double*)(lds + 32768);   // [2][128]
    float*  epiRS = (float*)(lds + 34816);    // [2][128]
    double* epiCM = (double*)(lds + 35840);   // [2][128]
    float*  epiCS = (float*)(lds + 37888);    // [2][128]
    double* lser_sh = (double*)(lds + 38912); // [128]
    double* lsec_sh = (double*)(lds + 39936); // [128]

    if (PASS == 2) {
        if (t < 128)      lser_sh[t] = lse_row[(size_t)n * LDIM + tileM * TILE + t];
        else if (t < 256) lsec_sh[t - 128] = lse_col[(size_t)n * LDIM + tileN * TILE + (t - 128)];
    }

    const i32x16 zero16 = {0,0,0,0,0,0,0,0,0,0,0,0,0,0,0,0};
    i32x16 acc0[2][2], acc1[2][2];
#pragma unroll
    for (int a = 0; a < 2; a++)
#pragma unroll
        for (int b = 0; b < 2; b++) { acc0[a][b] = zero16; acc1[a][b] = zero16; }

    // staging map: 4 granules (16B) per thread per chunk; LDS position encodes
    // pos = blk*64 + (rr&7) + 8*(kg*4 + (rr>>3)) so 8 consecutive read lanes
    // hit 8 distinct 16B bank-groups.
    const char* srcB[4];
    int dstoff[4];
#pragma unroll
    for (int q = 0; q < 4; q++) {
        int gl = q * 512 + t;
        int isB = gl >> 10;
        int g2 = gl & 1023;
        int plane = g2 >> 8;
        int gidx = g2 & 255;
        int blk = gidx >> 6, w6 = gidx & 63;
        int h = w6 >> 3;
        int kgg = h >> 2;
        int rr = (h & 3) * 8 + (w6 & 7);
        int r = blk * 32 + rr;
        int row0 = isB ? tileN * TILE : tileM * TILE;
        size_t inOff = isB ? DIG2_OFF : DIG1_OFF;
        srcB[q] = dig + inOff + (size_t)plane * 4194304u
                + ((size_t)n * LDIM + row0 + r) * 32 + kgg * 16;
        dstoff[q] = isB * 16384 + plane * 4096 + gidx * 16;
    }

    int4 stg[4];
#pragma unroll
    for (int q = 0; q < 4; q++) stg[q] = *(const int4*)srcB[q];

    const int posL = (l31 & 7) + 8 * (kg * 4 + (l31 >> 3));

    for (int kc = 0; kc < 4; ++kc) {
        __syncthreads();
#pragma unroll
        for (int q = 0; q < 4; q++) *(int4*)(lds + dstoff[q]) = stg[q];
        __syncthreads();
        if (kc < 3) {
#pragma unroll
            for (int q = 0; q < 4; q++)
                stg[q] = *(const int4*)(srcB[q] + (size_t)(kc + 1) * 1048576u);
        }
        i32x4 aF[4][2], bF[4][2];
#pragma unroll
        for (int p = 0; p < 4; p++) {
#pragma unroll
            for (int sm = 0; sm < 2; sm++) {
                int posA = (regR * 2 + sm) * 64 + posL;
                aF[p][sm] = *(const i32x4*)(lds + p * 4096 + posA * 16);
                int posB = (regC * 2 + sm) * 64 + posL;
                bF[p][sm] = *(const i32x4*)(lds + 16384 + p * 4096 + posB * 16);
            }
        }
#pragma unroll
        for (int sm = 0; sm < 2; sm++) {
#pragma unroll
            for (int sn = 0; sn < 2; sn++) {
                if (bg == 0) {
                    acc0[sm][sn] = mfma_i8(aF[0][sm], bF[0][sn], acc0[sm][sn]);   // s=0
                    acc1[sm][sn] = mfma_i8(aF[0][sm], bF[3][sn], acc1[sm][sn]);   // s=3
                    acc1[sm][sn] = mfma_i8(aF[1][sm], bF[2][sn], acc1[sm][sn]);
                    acc1[sm][sn] = mfma_i8(aF[2][sm], bF[1][sn], acc1[sm][sn]);
                    acc1[sm][sn] = mfma_i8(aF[3][sm], bF[0][sn], acc1[sm][sn]);
                } else {
                    acc0[sm][sn] = mfma_i8(aF[0][sm], bF[1][sn], acc0[sm][sn]);   // s=1
                    acc0[sm][sn] = mfma_i8(aF[1][sm], bF[0][sn], acc0[sm][sn]);
                    acc1[sm][sn] = mfma_i8(aF[0][sm], bF[2][sn], acc1[sm][sn]);   // s=2
                    acc1[sm][sn] = mfma_i8(aF[1][sm], bF[1][sn], acc1[sm][sn]);
                    acc1[sm][sn] = mfma_i8(aF[2][sm], bF[0][sn], acc1[sm][sn]);
                }
            }
        }
    }

    // ---- epilogue: bank exchange + fp64 recombination ----
    double cm[2] = {-1e300, -1e300};
    float cs[2] = {0.f, 0.f};
    u64 bestc[2] = {0ull, 0ull};
    const int exbase = (wave & 3) * 8192;

    for (int sm = 0; sm < 2; sm++) {
        double lam[2][16];
#pragma unroll
        for (int sn = 0; sn < 2; sn++) {
            __syncthreads();
            if (bg == 0) {
#pragma unroll
                for (int r = 0; r < 16; r++) {
                    *(int*)(lds + exbase + r * 256 + lane * 4)        = acc0[sm][sn][r];
                    *(int*)(lds + exbase + 4096 + r * 256 + lane * 4) = acc1[sm][sn][r];
                }
            }
            __syncthreads();
            if (bg == 1) {
#pragma unroll
                for (int r = 0; r < 16; r++) {
                    int T0 = *(const int*)(lds + exbase + r * 256 + lane * 4);
                    int T3 = *(const int*)(lds + exbase + 4096 + r * 256 + lane * 4);
                    int T1 = acc0[sm][sn][r];
                    int T2 = acc1[sm][sn][r];
                    // lambda = dot/TEMP = 10 * 2^-50 * sum(A*B)
                    lam[sn][r] = 10.0 * ((double)T0 * 0.00390625
                                       + (double)T1 * 3.0517578125e-05
                                       + (double)T2 * 2.384185791015625e-07
                                       + (double)T3 * 1.862645149230957e-09);
                }
            }
        }
        if (bg == 1) {
            if (PASS == 1) {
#pragma unroll
                for (int r = 0; r < 16; r++) {
                    double rm = fmax(lam[0][r], lam[1][r]);
#pragma unroll
                    for (int m = 1; m < 32; m <<= 1) rm = fmax(rm, __shfl_xor(rm, m));
                    float rs = expf((float)(lam[0][r] - rm)) + expf((float)(lam[1][r] - rm));
#pragma unroll
                    for (int m = 1; m < 32; m <<= 1) rs += __shfl_xor(rs, m);
                    if (l31 == 0) {
                        int rloc = regR * 64 + sm * 32 + (r & 3) + 8 * (r >> 2) + 4 * kg;
                        epiRM[regC * 128 + rloc] = rm;
                        epiRS[regC * 128 + rloc] = rs;
                    }
                }
#pragma unroll
                for (int sn = 0; sn < 2; sn++) {
#pragma unroll
                    for (int r = 0; r < 16; r++) {
                        double v = lam[sn][r];
                        double nm = fmax(cm[sn], v);
                        cs[sn] = cs[sn] * expf((float)(cm[sn] - nm)) + expf((float)(v - nm));
                        cm[sn] = nm;
                    }
                }
            } else {
#pragma unroll
                for (int r = 0; r < 16; r++) {
                    int rloc = regR * 64 + sm * 32 + (r & 3) + 8 * (r >> 2) + 4 * kg;
                    double lr = lser_sh[rloc];
                    u64 bestr = 0ull;
#pragma unroll
                    for (int sn = 0; sn < 2; sn++) {
                        int cloc = regC * 64 + sn * 32 + l31;
                        float gf = (float)(2.0 * lam[sn][r] - lr - lsec_sh[cloc]);
                        u64 key = ((u64)fkey(gf)) << 32;
                        u64 pr = key | (uint32)(~(uint32)(tileN * TILE + cloc));
                        if (pr > bestr) bestr = pr;
                        u64 pc = key | (uint32)(~(uint32)(tileM * TILE + rloc));
                        if (pc > bestc[sn]) bestc[sn] = pc;
                    }
#pragma unroll
                    for (int m = 1; m < 32; m <<= 1) { u64 o = __shfl_xor(bestr, m); if (o > bestr) bestr = o; }
                    if (l31 == 0) atomicMax(&rowpack[(size_t)n * LDIM + tileM * TILE + rloc], bestr);
                }
            }
        }
    }
    if (bg == 1) {
        if (PASS == 1) {
#pragma unroll
            for (int sn = 0; sn < 2; sn++) {
                double om = __shfl_xor(cm[sn], 32);
                float os = __shfl_xor(cs[sn], 32);
                double nm = fmax(cm[sn], om);
                float ns = cs[sn] * expf((float)(cm[sn] - nm)) + os * expf((float)(om - nm));
                if (kg == 0) {
                    int c = regC * 64 + sn * 32 + l31;
                    epiCM[regR * 128 + c] = nm;
                    epiCS[regR * 128 + c] = ns;
                }
            }
        } else {
#pragma unroll
            for (int sn = 0; sn < 2; sn++) {
                u64 o = __shfl_xor(bestc[sn], 32);
                if (o > bestc[sn]) bestc[sn] = o;
                if (kg == 0)
                    atomicMax(&colpack[(size_t)n * LDIM + tileN * TILE + regC * 64 + sn * 32 + l31], bestc[sn]);
            }
        }
    }
    if (PASS == 1) {
        __syncthreads();
        if (t < 128) {
            double m0 = epiRM[t], m1 = epiRM[128 + t];
            double M = fmax(m0, m1);
            float S = epiRS[t] * expf((float)(m0 - M)) + epiRS[128 + t] * expf((float)(m1 - M));
            float Mf = (float)M;
            S = S * expf((float)(M - (double)Mf));
            rowpart[((size_t)n * LDIM + tileM * TILE + t) * 32 + tileN] = make_float2(Mf, S);
        } else if (t < 256) {
            int c = t - 128;
            double m0 = epiCM[c], m1 = epiCM[128 + c];
            double M = fmax(m0, m1);
            float S = epiCS[c] * expf((float)(m0 - M)) + epiCS[128 + c] * expf((float)(m1 - M));
            float Mf = (float)M;
            S = S * expf((float)(M - (double)Mf));
            colpart[((size_t)n * LDIM + tileN * TILE + c) * 32 + tileM] = make_float2(Mf, S);
        }
    }
}

__global__ __launch_bounds__(256) void merge_kernel(
    const float2* __restrict__ rowpart, const float2* __restrict__ colpart,
    double* __restrict__ lse_row, double* __restrict__ lse_col)
{
    int idx = blockIdx.x * 256 + threadIdx.x;   // 0..65535
    const float2* src = (idx < BATCH * LDIM) ? rowpart : colpart;
    double* dst = (idx < BATCH * LDIM) ? lse_row : lse_col;
    int i = idx & (BATCH * LDIM - 1);
    double M = -1e300;
#pragma unroll
    for (int j = 0; j < 32; j++) M = fmax(M, (double)src[(size_t)i * 32 + j].x);
    double S = 0.0;
#pragma unroll
    for (int j = 0; j < 32; j++) {
        float2 ms = src[(size_t)i * 32 + j];
        S += (double)ms.y * exp((double)ms.x - M);
    }
    dst[i] = M + log(S);
}

__global__ __launch_bounds__(256) void out_kernel(
    const float* __restrict__ f1, const float* __restrict__ f2,
    const u64* __restrict__ rowpack, const u64* __restrict__ colpack,
    float* __restrict__ out)
{
    int n = blockIdx.y;
    int l0 = blockIdx.x * 64;
    int t = threadIdx.x;
    __shared__ int s_sh[64];
    __shared__ int m_sh[64];
    __shared__ float tile[64][129];
    if (t < 64) {
        u64 rp = rowpack[(size_t)n * LDIM + l0 + t];
        uint32 skey = (uint32)(rp >> 32);
        uint32 s = (~(uint32)rp) & 4095u;
        u64 cp = colpack[(size_t)n * LDIM + s];
        double g = (double)keyf(skey);
        int match = (((uint32)(cp >> 32)) == skey) && (exp(g) > 0.2);
        s_sh[t] = (int)s;
        m_sh[t] = match;
    }
    __syncthreads();
#pragma unroll
    for (int i = 0; i < 32; i++) {
        int idx = i * 256 + t;
        int lloc = idx >> 7, ch = idx & 127;
        float v = f1[((size_t)n * LDIM + l0 + lloc) * CDIM + ch];
        if (m_sh[lloc]) v -= f2[((size_t)n * LDIM + s_sh[lloc]) * CDIM + ch];
        tile[lloc][ch] = v;
    }
    __syncthreads();
#pragma unroll
    for (int i = 0; i < 32; i++) {
        int ch = i * 4 + (t >> 6), lw = t & 63;
        out[((size_t)n * CDIM + ch) * LDIM + l0 + lw] = tile[lw][ch];
    }
}

extern "C" void kernel_launch(void* const* d_in, const int* in_sizes, int n_in,
                              void* d_out, int out_size, void* d_ws, size_t ws_size,
                              hipStream_t stream)
{
    const float* f1 = (const float*)d_in[0];
    const float* f2 = (const float*)d_in[1];
    float* out = (float*)d_out;

    if (ws_size < WS_NEEDED) {
        fill_sentinel<<<(out_size + 255) / 256, 256, 0, stream>>>(out, out_size);
        return;
    }

    char* ws = (char*)d_ws;
    char* dig = ws;
    float2* rowpart = (float2*)(ws + ROWPART_OFF);
    float2* colpart = (float2*)(ws + COLPART_OFF);
    double* lse_row = (double*)(ws + LSER_OFF);
    double* lse_col = (double*)(ws + LSEC_OFF);
    u64* rowpack = (u64*)(ws + RPACK_OFF);
    u64* colpack = (u64*)(ws + CPACK_OFF);

    quant_kernel<<<dim3(8192), dim3(256), 0, stream>>>(f1, f2, dig);
    init_packs<<<dim3(128), dim3(256), 0, stream>>>(rowpack, colpack);
    gemm_kernel<1><<<dim3(32, 32, BATCH), dim3(512), 0, stream>>>(
        dig, rowpart, colpart, lse_row, lse_col, rowpack, colpack);
    merge_kernel<<<dim3(256), dim3(256), 0, stream>>>(rowpart, colpart, lse_row, lse_col);
    gemm_kernel<2><<<dim3(32, 32, BATCH), dim3(512), 0, stream>>>(
        dig, rowpart, colpart, lse_row, lse_col, rowpack, colpack);
    out_kernel<<<dim3(LDIM / 64, BATCH), dim3(256), 0, stream>>>(
        f1, f2, rowpack, colpack, out);
}

// Round 3
// 1172.150 us; speedup vs baseline: 4.3156x; 4.3156x over previous
//
#include <hip/hip_runtime.h>
#include <stdint.h>

typedef unsigned int uint32;
typedef unsigned long long u64;

#define BATCH 8
#define LDIM 4096
#define CDIM 128

typedef __attribute__((ext_vector_type(4))) int i32x4;
typedef __attribute__((ext_vector_type(16))) int i32x16;

// ---- workspace layout (bytes) ---- (total identical to round 2: known to fit)
#define DIG1_OFF    0ull          /* i8 digits f1, LDS-order swizzled: 16 MB */
#define DIG2_OFF    16777216ull   /* i8 digits f2 */
#define ROWPART_OFF 33554432ull   /* float2 [8][4096][32] = 8 MB */
#define COLPART_OFF 41943040ull   /* float2 [8][4096][32] = 8 MB */
#define LSER_OFF    50331648ull   /* double [8][4096] */
#define LSEC_OFF    50593792ull
#define RPACK_OFF   50855936ull   /* u64 [8][4096] */
#define CPACK_OFF   51118080ull
#define WS_NEEDED   51380224ull

// lam = 10*(T01*2^-15 + T23*2^-29), T01 = T0*128+T1 (exact int), T23 = T2*128+T3
#define TEN_P15 3.0517578125e-04
#define TEN_P29 1.862645149230957e-08

#define CROW(r, kgv) (((r)&3) + 8*((r)>>2) + 4*(kgv))

__device__ __forceinline__ uint32 fkey(float f) {
    uint32 u = __float_as_uint(f);
    return (u & 0x80000000u) ? ~u : (u | 0x80000000u);
}
__device__ __forceinline__ float keyf(uint32 k) {
    uint32 u = (k & 0x80000000u) ? (k ^ 0x80000000u) : ~k;
    return __uint_as_float(u);
}
__device__ __forceinline__ i32x16 mfma_i8(i32x4 a, i32x4 b, i32x16 c) {
    return __builtin_amdgcn_mfma_i32_32x32x32_i8(a, b, c, 0, 0, 0);
}
__device__ __forceinline__ void load_lds16(const char* g, char* l) {
    __builtin_amdgcn_global_load_lds((__attribute__((address_space(1))) void*)(g),
                                     (__attribute__((address_space(3))) void*)(l), 16, 0, 0);
}
__device__ __forceinline__ u64 umax64(u64 a, u64 b) { return a > b ? a : b; }

__global__ void fill_sentinel(float* out, int nelem) {
    int i = blockIdx.x * 256 + threadIdx.x;
    if (i < nelem) out[i] = 12345.0f;
}

__global__ void init_packs(u64* __restrict__ rowpack, u64* __restrict__ colpack) {
    int idx = blockIdx.x * 256 + threadIdx.x;
    if (idx < BATCH * LDIM) { rowpack[idx] = 0ull; colpack[idx] = 0ull; }
}

// Quantize fp32 -> 4 exact base-128 signed digits of round(x*2^25), written in
// the exact [n][blk64][kc][plane][rb][lane] LDS/fragment order (lane=kg*32+l31).
__global__ __launch_bounds__(256) void quant_kernel(const float* __restrict__ f1,
                                                    const float* __restrict__ f2,
                                                    char* __restrict__ dig)
{
    int tid = blockIdx.x * 256 + threadIdx.x;   // 2^19 threads
    int l31 = tid & 31;
    int kg  = (tid >> 5) & 1;
    int kc  = (tid >> 6) & 3;
    int rb  = (tid >> 8) & 1;
    int blk = (tid >> 9) & 63;
    int n   = (tid >> 15) & 7;
    int inp = tid >> 18;
    int row = blk * 64 + rb * 32 + l31;

    const float* src = (inp ? f2 : f1) + ((size_t)(n * LDIM + row)) * CDIM + kc * 32 + kg * 16;
    char* dstc = dig + (inp ? DIG2_OFF : DIG1_OFF)
               + (((size_t)n * 64 + blk) * 4 + kc) * 8192;   // chunk base
    int gpos = rb * 64 + kg * 32 + l31;                      // granule pos within [rb][lane]

    float4 v0 = ((const float4*)src)[0];
    float4 v1 = ((const float4*)src)[1];
    float4 v2 = ((const float4*)src)[2];
    float4 v3 = ((const float4*)src)[3];
    float xs[16] = {v0.x,v0.y,v0.z,v0.w, v1.x,v1.y,v1.z,v1.w,
                    v2.x,v2.y,v2.z,v2.w, v3.x,v3.y,v3.z,v3.w};
    uint32 wds[4][4] = {{0,0,0,0},{0,0,0,0},{0,0,0,0},{0,0,0,0}};
#pragma unroll
    for (int e = 0; e < 16; e++) {
        int q = __float2int_rn(xs[e] * 33554432.0f);
        int d0 = (q + (1 << 20)) >> 21; q -= d0 << 21;
        int d1 = (q + (1 << 13)) >> 14; q -= d1 << 14;
        int d2 = (q + (1 << 6)) >> 7;   q -= d2 << 7;
        int sh = (e & 3) * 8;
        wds[0][e >> 2] |= (uint32)(d0 & 255) << sh;
        wds[1][e >> 2] |= (uint32)(d1 & 255) << sh;
        wds[2][e >> 2] |= (uint32)(d2 & 255) << sh;
        wds[3][e >> 2] |= (uint32)(q  & 255) << sh;
    }
#pragma unroll
    for (int p = 0; p < 4; p++) {
        *(int4*)(dstc + (size_t)(p * 128 + gpos) * 16) =
            make_int4(wds[p][0], wds[p][1], wds[p][2], wds[p][3]);
    }
}

// PASS 1: exact i8-digit GEMM -> per-128-tile (max,sumexp) row/col partials.
// PASS 2: recompute -> packed argmax keys of g = 2*lam - lse_r - lse_c.
// 256 threads = 4 waves = (bg in {0,1}) x (rr in {0,1}); 128x128 tile as 4
// sequential 64x64 quadrants; bg0 accumulates T0,T3 banks, bg1 T1,T2.
template <int PASS>
__global__ __launch_bounds__(256, 2) void gemm_kernel(
    const char* __restrict__ dig,
    float2* __restrict__ rowpart, float2* __restrict__ colpart,
    const double* __restrict__ lse_row, const double* __restrict__ lse_col,
    u64* __restrict__ rowpack, u64* __restrict__ colpack)
{
    __shared__ __align__(16) char sm[38400];
    // [0,8192)=Abuf0 [8192,16384)=Abuf1 [16384,24576)=Bbuf0 [24576,32768)=Bbuf1
    float* rowHalfM = (float*)(sm + 32768);   // [2][64]
    float* rowHalfS = (float*)(sm + 33280);
    float* colHalfM = (float*)(sm + 33792);
    float* colHalfS = (float*)(sm + 34304);
    u64* rowHalfK   = (u64*)(sm + 32768);     // [2][64] (pass2 alias)
    u64* colHalfK   = (u64*)(sm + 33792);
    float* rowRunM  = (float*)(sm + 34816);   // [64]
    float* rowRunS  = (float*)(sm + 35072);
    float* colRunM  = (float*)(sm + 35328);   // [2][64]
    float* colRunS  = (float*)(sm + 35840);
    u64* rowRunK    = (u64*)(sm + 34816);     // [64]
    u64* colRunK    = (u64*)(sm + 35328);     // [2][64]
    double* lser_sh = (double*)(sm + 36352);  // [128]
    double* lsec_sh = (double*)(sm + 37376);  // [128]

    int wg = blockIdx.x;
    int swz = (wg & 7) * 1024 + (wg >> 3);    // XCD-contiguous: one batch per XCD
    int n  = swz >> 10;
    int tM = (swz >> 5) & 31;
    int tN = swz & 31;

    const int t = threadIdx.x;
    const int lane = t & 63, wave = t >> 6;
    const int bg = wave >> 1, rr = wave & 1;
    const int l31 = lane & 31, kg = lane >> 5;

    if (PASS == 2) {
        if (t < 128)      lser_sh[t] = lse_row[(size_t)n * LDIM + tM * 128 + t];
        else              lsec_sh[t - 128] = lse_col[(size_t)n * LDIM + tN * 128 + (t - 128)];
    }

    const i32x16 zero16 = {0,0,0,0,0,0,0,0,0,0,0,0,0,0,0,0};
    i32x16 acc0[2], acc1[2];   // [cb]; bg0: T0,T3  bg1: T1,T2
    acc0[0] = zero16; acc0[1] = zero16; acc1[0] = zero16; acc1[1] = zero16;

    auto stage_step = [&](int s, int buf) {
        int q = s >> 2, kc = s & 3;
        int blkA = tM * 2 + (q >> 1);
        int blkB = tN * 2 + (q & 1);
        const char* gA = dig + DIG1_OFF + ((((size_t)n * 64 + blkA) * 4 + kc)) * 8192
                       + wave * 2048 + lane * 16;
        const char* gB = dig + DIG2_OFF + ((((size_t)n * 64 + blkB) * 4 + kc)) * 8192
                       + wave * 2048 + lane * 16;
        char* lA = sm + buf * 8192 + wave * 2048;
        char* lB = sm + 16384 + buf * 8192 + wave * 2048;
        load_lds16(gA, lA);        load_lds16(gA + 1024, lA + 1024);
        load_lds16(gB, lB);        load_lds16(gB + 1024, lB + 1024);
    };

    stage_step(0, 0);

    for (int s = 0; s < 16; ++s) {
        int q = s >> 2, kc = s & 3;
        int buf = s & 1;
        __syncthreads();            // staged data ready; prev frag reads done
        if (s < 15) stage_step(s + 1, (s + 1) & 1);

        const char* Ab = sm + buf * 8192;
        const char* Bb = sm + 16384 + buf * 8192;
        i32x4 aF[4], bF[2][4];
#pragma unroll
        for (int p = 0; p < 4; p++)
            aF[p] = *(const i32x4*)(Ab + (size_t)(p * 2048 + rr * 1024) + lane * 16);
#pragma unroll
        for (int cb = 0; cb < 2; cb++)
#pragma unroll
            for (int p = 0; p < 4; p++)
                bF[cb][p] = *(const i32x4*)(Bb + (size_t)(p * 2048 + cb * 1024) + lane * 16);

#pragma unroll
        for (int cb = 0; cb < 2; cb++) {
            if (bg == 0) {
                acc0[cb] = mfma_i8(aF[0], bF[cb][0], acc0[cb]);   // T0
                acc1[cb] = mfma_i8(aF[0], bF[cb][3], acc1[cb]);   // T3
                acc1[cb] = mfma_i8(aF[1], bF[cb][2], acc1[cb]);
                acc1[cb] = mfma_i8(aF[2], bF[cb][1], acc1[cb]);
                acc1[cb] = mfma_i8(aF[3], bF[cb][0], acc1[cb]);
            } else {
                acc0[cb] = mfma_i8(aF[0], bF[cb][1], acc0[cb]);   // T1
                acc0[cb] = mfma_i8(aF[1], bF[cb][0], acc0[cb]);
                acc1[cb] = mfma_i8(aF[0], bF[cb][2], acc1[cb]);   // T2
                acc1[cb] = mfma_i8(aF[1], bF[cb][1], acc1[cb]);
                acc1[cb] = mfma_i8(aF[2], bF[cb][0], acc1[cb]);
            }
        }

        if (kc == 3) {
            // ---- quadrant epilogue; exchange uses buf1 (just-freed compute buf) ----
            int rq = q >> 1, cq = q & 1;
            char* ex = sm + ((rr == 0) ? 8192 : 24576);
            int T0v[16], T1v[16], T2v[16], T3v[16];

            __syncthreads();
            if (bg == 0) {    // send (T0,T3) of cb=1
#pragma unroll
                for (int r4 = 0; r4 < 4; r4++) {
                    *(int4*)(ex + r4 * 1024 + lane * 16) =
                        make_int4(acc0[1][r4*4+0], acc0[1][r4*4+1], acc0[1][r4*4+2], acc0[1][r4*4+3]);
                    *(int4*)(ex + 4096 + r4 * 1024 + lane * 16) =
                        make_int4(acc1[1][r4*4+0], acc1[1][r4*4+1], acc1[1][r4*4+2], acc1[1][r4*4+3]);
                }
            }
            __syncthreads();
            if (bg == 1) {
#pragma unroll
                for (int r4 = 0; r4 < 4; r4++) {
                    int4 a = *(const int4*)(ex + r4 * 1024 + lane * 16);
                    int4 b = *(const int4*)(ex + 4096 + r4 * 1024 + lane * 16);
                    T0v[r4*4+0]=a.x; T0v[r4*4+1]=a.y; T0v[r4*4+2]=a.z; T0v[r4*4+3]=a.w;
                    T3v[r4*4+0]=b.x; T3v[r4*4+1]=b.y; T3v[r4*4+2]=b.z; T3v[r4*4+3]=b.w;
                }
            }
            __syncthreads();
            if (bg == 1) {    // send (T1,T2) of cb=0
#pragma unroll
                for (int r4 = 0; r4 < 4; r4++) {
                    *(int4*)(ex + r4 * 1024 + lane * 16) =
                        make_int4(acc0[0][r4*4+0], acc0[0][r4*4+1], acc0[0][r4*4+2], acc0[0][r4*4+3]);
                    *(int4*)(ex + 4096 + r4 * 1024 + lane * 16) =
                        make_int4(acc1[0][r4*4+0], acc1[0][r4*4+1], acc1[0][r4*4+2], acc1[0][r4*4+3]);
                }
            }
            __syncthreads();
            if (bg == 0) {
#pragma unroll
                for (int r4 = 0; r4 < 4; r4++) {
                    int4 a = *(const int4*)(ex + r4 * 1024 + lane * 16);
                    int4 b = *(const int4*)(ex + 4096 + r4 * 1024 + lane * 16);
                    T1v[r4*4+0]=a.x; T1v[r4*4+1]=a.y; T1v[r4*4+2]=a.z; T1v[r4*4+3]=a.w;
                    T2v[r4*4+0]=b.x; T2v[r4*4+1]=b.y; T2v[r4*4+2]=b.z; T2v[r4*4+3]=b.w;
                }
#pragma unroll
                for (int r = 0; r < 16; r++) { T0v[r] = acc0[0][r]; T3v[r] = acc1[0][r]; }
            } else {
#pragma unroll
                for (int r = 0; r < 16; r++) { T1v[r] = acc0[1][r]; T2v[r] = acc1[1][r]; }
            }
            acc0[0] = zero16; acc0[1] = zero16; acc1[0] = zero16; acc1[1] = zero16;

            double lam[16]; float lf[16];
#pragma unroll
            for (int r = 0; r < 16; r++) {
                int t01 = T0v[r] * 128 + T1v[r];
                int t23 = T2v[r] * 128 + T3v[r];
                lam[r] = (double)t01 * TEN_P15 + (double)t23 * TEN_P29;
                lf[r] = (float)lam[r];
            }

            if (PASS == 1) {
                float rm[16], rs[16];
#pragma unroll
                for (int r = 0; r < 16; r++) rm[r] = lf[r];
#pragma unroll
                for (int m = 1; m < 32; m <<= 1)
#pragma unroll
                    for (int r = 0; r < 16; r++) rm[r] = fmaxf(rm[r], __shfl_xor(rm[r], m));
#pragma unroll
                for (int r = 0; r < 16; r++) rs[r] = expf((float)(lam[r] - (double)rm[r]));
#pragma unroll
                for (int m = 1; m < 32; m <<= 1)
#pragma unroll
                    for (int r = 0; r < 16; r++) rs[r] += __shfl_xor(rs[r], m);
                if (l31 == 0) {
#pragma unroll
                    for (int r = 0; r < 16; r++) {
                        int rl = rr * 32 + CROW(r, kg);
                        rowHalfM[bg * 64 + rl] = rm[r];
                        rowHalfS[bg * 64 + rl] = rs[r];
                    }
                }
                float cm = -3.4e38f;
#pragma unroll
                for (int r = 0; r < 16; r++) cm = fmaxf(cm, lf[r]);
                cm = fmaxf(cm, __shfl_xor(cm, 32));
                float cs = 0.f;
#pragma unroll
                for (int r = 0; r < 16; r++) cs += expf((float)(lam[r] - (double)cm));
                cs += __shfl_xor(cs, 32);
                if (kg == 0) {
                    colHalfM[rr * 64 + bg * 32 + l31] = cm;
                    colHalfS[rr * 64 + bg * 32 + l31] = cs;
                }
                __syncthreads();
                if (t < 64) {
                    float m0 = rowHalfM[t], m1 = rowHalfM[64 + t];
                    float s0 = rowHalfS[t], s1 = rowHalfS[64 + t];
                    float M = fmaxf(m0, m1);
                    float S = s0 * expf(m0 - M) + s1 * expf(m1 - M);
                    if (cq == 0) { rowRunM[t] = M; rowRunS[t] = S; }
                    else {
                        float pM = rowRunM[t], pS = rowRunS[t];
                        float F = fmaxf(M, pM);
                        float FS = S * expf(M - F) + pS * expf(pM - F);
                        rowpart[((size_t)n * LDIM + tM * 128 + rq * 64 + t) * 32 + tN] = make_float2(F, FS);
                    }
                } else if (t < 128) {
                    int c = t - 64;
                    float m0 = colHalfM[c], m1 = colHalfM[64 + c];
                    float s0 = colHalfS[c], s1 = colHalfS[64 + c];
                    float M = fmaxf(m0, m1);
                    float S = s0 * expf(m0 - M) + s1 * expf(m1 - M);
                    if (rq == 0) { colRunM[cq * 64 + c] = M; colRunS[cq * 64 + c] = S; }
                    else {
                        float pM = colRunM[cq * 64 + c], pS = colRunS[cq * 64 + c];
                        float F = fmaxf(M, pM);
                        float FS = S * expf(M - F) + pS * expf(pM - F);
                        colpart[((size_t)n * LDIM + tN * 128 + cq * 64 + c) * 32 + tM] = make_float2(F, FS);
                    }
                }
            } else {
                int colg = tN * 128 + cq * 64 + bg * 32 + l31;
                double lc = lsec_sh[cq * 64 + bg * 32 + l31];
                u64 rowk[16];
                u64 ck = 0ull;
#pragma unroll
                for (int r = 0; r < 16; r++) {
                    int rowl = rq * 64 + rr * 32 + CROW(r, kg);
                    float gf = (float)(2.0 * lam[r] - lser_sh[rowl] - lc);
                    u64 key = ((u64)fkey(gf)) << 32;
                    rowk[r] = key | (uint32)(~(uint32)colg);
                    ck = umax64(ck, key | (uint32)(~(uint32)(tM * 128 + rowl)));
                }
#pragma unroll
                for (int m = 1; m < 32; m <<= 1)
#pragma unroll
                    for (int r = 0; r < 16; r++) rowk[r] = umax64(rowk[r], __shfl_xor(rowk[r], m));
                if (l31 == 0) {
#pragma unroll
                    for (int r = 0; r < 16; r++)
                        rowHalfK[bg * 64 + rr * 32 + CROW(r, kg)] = rowk[r];
                }
                ck = umax64(ck, __shfl_xor(ck, 32));
                if (kg == 0) colHalfK[rr * 64 + bg * 32 + l31] = ck;
                __syncthreads();
                if (t < 64) {
                    u64 b = umax64(rowHalfK[t], rowHalfK[64 + t]);
                    if (cq == 0) rowRunK[t] = b;
                    else {
                        b = umax64(b, rowRunK[t]);
                        atomicMax(&rowpack[(size_t)n * LDIM + tM * 128 + rq * 64 + t], b);
                    }
                } else if (t < 128) {
                    int c = t - 64;
                    u64 b = umax64(colHalfK[c], colHalfK[64 + c]);
                    if (rq == 0) colRunK[cq * 64 + c] = b;
                    else {
                        b = umax64(b, colRunK[cq * 64 + c]);
                        atomicMax(&colpack[(size_t)n * LDIM + tN * 128 + cq * 64 + c], b);
                    }
                }
            }
        }
    }
}

__global__ __launch_bounds__(256) void merge_kernel(
    const float2* __restrict__ rowpart, const float2* __restrict__ colpart,
    double* __restrict__ lse_row, double* __restrict__ lse_col)
{
    int idx = blockIdx.x * 256 + threadIdx.x;   // 0..65535
    const float2* src = (idx < BATCH * LDIM) ? rowpart : colpart;
    double* dst = (idx < BATCH * LDIM) ? lse_row : lse_col;
    int i = idx & (BATCH * LDIM - 1);
    double M = -1e300;
#pragma unroll
    for (int j = 0; j < 32; j++) M = fmax(M, (double)src[(size_t)i * 32 + j].x);
    double S = 0.0;
#pragma unroll
    for (int j = 0; j < 32; j++) {
        float2 ms = src[(size_t)i * 32 + j];
        S += (double)ms.y * exp((double)ms.x - M);
    }
    dst[i] = M + log(S);
}

__global__ __launch_bounds__(256) void out_kernel(
    const float* __restrict__ f1, const float* __restrict__ f2,
    const u64* __restrict__ rowpack, const u64* __restrict__ colpack,
    float* __restrict__ out)
{
    int n = blockIdx.y;
    int l0 = blockIdx.x * 64;
    int t = threadIdx.x;
    __shared__ int s_sh[64];
    __shared__ int m_sh[64];
    __shared__ float tile[64][129];
    if (t < 64) {
        u64 rp = rowpack[(size_t)n * LDIM + l0 + t];
        uint32 skey = (uint32)(rp >> 32);
        uint32 s = (~(uint32)rp) & 4095u;
        u64 cp = colpack[(size_t)n * LDIM + s];
        double g = (double)keyf(skey);
        int match = (((uint32)(cp >> 32)) == skey) && (exp(g) > 0.2);
        s_sh[t] = (int)s;
        m_sh[t] = match;
    }
    __syncthreads();
#pragma unroll
    for (int i = 0; i < 32; i++) {
        int idx = i * 256 + t;
        int lloc = idx >> 7, ch = idx & 127;
        float v = f1[((size_t)n * LDIM + l0 + lloc) * CDIM + ch];
        if (m_sh[lloc]) v -= f2[((size_t)n * LDIM + s_sh[lloc]) * CDIM + ch];
        tile[lloc][ch] = v;
    }
    __syncthreads();
#pragma unroll
    for (int i = 0; i < 32; i++) {
        int ch = i * 4 + (t >> 6), lw = t & 63;
        out[((size_t)n * CDIM + ch) * LDIM + l0 + lw] = tile[lw][ch];
    }
}

extern "C" void kernel_launch(void* const* d_in, const int* in_sizes, int n_in,
                              void* d_out, int out_size, void* d_ws, size_t ws_size,
                              hipStream_t stream)
{
    const float* f1 = (const float*)d_in[0];
    const float* f2 = (const float*)d_in[1];
    float* out = (float*)d_out;

    if (ws_size < WS_NEEDED) {
        fill_sentinel<<<(out_size + 255) / 256, 256, 0, stream>>>(out, out_size);
        return;
    }

    char* ws = (char*)d_ws;
    char* dig = ws;
    float2* rowpart = (float2*)(ws + ROWPART_OFF);
    float2* colpart = (float2*)(ws + COLPART_OFF);
    double* lse_row = (double*)(ws + LSER_OFF);
    double* lse_col = (double*)(ws + LSEC_OFF);
    u64* rowpack = (u64*)(ws + RPACK_OFF);
    u64* colpack = (u64*)(ws + CPACK_OFF);

    quant_kernel<<<dim3(2048), dim3(256), 0, stream>>>(f1, f2, dig);
    init_packs<<<dim3(128), dim3(256), 0, stream>>>(rowpack, colpack);
    gemm_kernel<1><<<dim3(8192), dim3(256), 0, stream>>>(
        dig, rowpart, colpart, lse_row, lse_col, rowpack, colpack);
    merge_kernel<<<dim3(256), dim3(256), 0, stream>>>(rowpart, colpart, lse_row, lse_col);
    gemm_kernel<2><<<dim3(8192), dim3(256), 0, stream>>>(
        dig, rowpart, colpart, lse_row, lse_col, rowpack, colpack);
    out_kernel<<<dim3(LDIM / 64, BATCH), dim3(256), 0, stream>>>(
        f1, f2, rowpack, colpack, out);
}

// Round 4
// 805.126 us; speedup vs baseline: 6.2829x; 1.4559x over previous
//
#include <hip/hip_runtime.h>
#include <stdint.h>

typedef unsigned int uint32;
typedef unsigned long long u64;

#define BATCH 8
#define LDIM 4096
#define CDIM 128

typedef __attribute__((ext_vector_type(4))) int i32x4;
typedef __attribute__((ext_vector_type(16))) int i32x16;

// ---- workspace layout (bytes) ----
#define DIG1_OFF    0ull          /* i8 digits f1, LDS-order: 16 MB */
#define DIG2_OFF    16777216ull   /* i8 digits f2 */
#define ROWPART_OFF 33554432ull   /* float2 [8][4096][32] = 8 MB */
#define COLPART_OFF 41943040ull   /* float2 [8][4096][32] = 8 MB */
#define LSER_OFF    50331648ull   /* double [8][4096] */
#define LSEC_OFF    50593792ull
#define RPACK_OFF   50855936ull   /* u64 [8][4096] */
#define CPACK_OFF   51118080ull
#define WS_NEEDED   51380224ull

#define TEN_P15 3.0517578125e-04
#define TEN_P29 1.862645149230957e-08

#define CROW(r, kgv) (((r)&3) + 8*((r)>>2) + 4*(kgv))

// ---- LDS layout (gemm kernel) ----
#define L_STAGE   0        /* A buf0/buf1, B buf0/buf1: 4 x 8KB */
#define L_TR      32768    /* 64 x 66 x 8B transpose/exchange region */
#define L_CSTAT   66560    /* 8 x 64 x 8B col partials */
#define L_RRUN    70656    /* 64 x 8B row running */
#define L_CRUN    71168    /* 128 x 8B col running */
#define L_LSER    72192    /* double[128] */
#define L_LSEC    73216    /* double[128] */
#define L_TOTAL   74240

__device__ __forceinline__ uint32 fkey(float f) {
    uint32 u = __float_as_uint(f);
    return (u & 0x80000000u) ? ~u : (u | 0x80000000u);
}
__device__ __forceinline__ float keyf(uint32 k) {
    uint32 u = (k & 0x80000000u) ? (k ^ 0x80000000u) : ~k;
    return __uint_as_float(u);
}
__device__ __forceinline__ i32x16 mfma_i8(i32x4 a, i32x4 b, i32x16 c) {
    return __builtin_amdgcn_mfma_i32_32x32x32_i8(a, b, c, 0, 0, 0);
}
__device__ __forceinline__ void load_lds16(const char* g, char* l) {
    __builtin_amdgcn_global_load_lds((__attribute__((address_space(1))) void*)(g),
                                     (__attribute__((address_space(3))) void*)(l), 16, 0, 0);
}
__device__ __forceinline__ u64 umax64(u64 a, u64 b) { return a > b ? a : b; }

__global__ void fill_sentinel(float* out, int nelem) {
    int i = blockIdx.x * 256 + threadIdx.x;
    if (i < nelem) out[i] = 12345.0f;
}

__global__ void init_packs(u64* __restrict__ rowpack, u64* __restrict__ colpack) {
    int idx = blockIdx.x * 256 + threadIdx.x;
    if (idx < BATCH * LDIM) { rowpack[idx] = 0ull; colpack[idx] = 0ull; }
}

// Quantize fp32 -> 4 exact base-128 signed digits of round(x*2^25) (unchanged).
__global__ __launch_bounds__(256) void quant_kernel(const float* __restrict__ f1,
                                                    const float* __restrict__ f2,
                                                    char* __restrict__ dig)
{
    int tid = blockIdx.x * 256 + threadIdx.x;
    int l31 = tid & 31;
    int kg  = (tid >> 5) & 1;
    int kc  = (tid >> 6) & 3;
    int rb  = (tid >> 8) & 1;
    int blk = (tid >> 9) & 63;
    int n   = (tid >> 15) & 7;
    int inp = tid >> 18;
    int row = blk * 64 + rb * 32 + l31;

    const float* src = (inp ? f2 : f1) + ((size_t)(n * LDIM + row)) * CDIM + kc * 32 + kg * 16;
    char* dstc = dig + (inp ? DIG2_OFF : DIG1_OFF)
               + (((size_t)n * 64 + blk) * 4 + kc) * 8192;
    int gpos = rb * 64 + kg * 32 + l31;

    float4 v0 = ((const float4*)src)[0];
    float4 v1 = ((const float4*)src)[1];
    float4 v2 = ((const float4*)src)[2];
    float4 v3 = ((const float4*)src)[3];
    float xs[16] = {v0.x,v0.y,v0.z,v0.w, v1.x,v1.y,v1.z,v1.w,
                    v2.x,v2.y,v2.z,v2.w, v3.x,v3.y,v3.z,v3.w};
    uint32 wds[4][4] = {{0,0,0,0},{0,0,0,0},{0,0,0,0},{0,0,0,0}};
#pragma unroll
    for (int e = 0; e < 16; e++) {
        int q = __float2int_rn(xs[e] * 33554432.0f);
        int d0 = (q + (1 << 20)) >> 21; q -= d0 << 21;
        int d1 = (q + (1 << 13)) >> 14; q -= d1 << 14;
        int d2 = (q + (1 << 6)) >> 7;   q -= d2 << 7;
        int sh = (e & 3) * 8;
        wds[0][e >> 2] |= (uint32)(d0 & 255) << sh;
        wds[1][e >> 2] |= (uint32)(d1 & 255) << sh;
        wds[2][e >> 2] |= (uint32)(d2 & 255) << sh;
        wds[3][e >> 2] |= (uint32)(q  & 255) << sh;
    }
#pragma unroll
    for (int p = 0; p < 4; p++) {
        *(int4*)(dstc + (size_t)(p * 128 + gpos) * 16) =
            make_int4(wds[p][0], wds[p][1], wds[p][2], wds[p][3]);
    }
}

// 8 waves = (bg, rr, cb). 128x128 tile as 4 sequential 64x64 quadrants.
// bg0 accumulates T0,T3 banks; bg1 T1,T2; exchange halves -> each lane
// finalizes 8 elements. Row stats/argmax via LDS transpose (stride 66).
template <int PASS>
__global__ __launch_bounds__(512, 4) void gemm_kernel(
    const char* __restrict__ dig,
    float2* __restrict__ rowpart, float2* __restrict__ colpart,
    const double* __restrict__ lse_row, const double* __restrict__ lse_col,
    u64* __restrict__ rowpack, u64* __restrict__ colpack)
{
    __shared__ __align__(16) char sm[L_TOTAL];
    double* lser_sh = (double*)(sm + L_LSER);
    double* lsec_sh = (double*)(sm + L_LSEC);

    int wg = blockIdx.x;
    int swz = (wg & 7) * 1024 + (wg >> 3);    // one batch per XCD
    int n  = swz >> 10;
    int tM = (swz >> 5) & 31;
    int tN = swz & 31;

    const int t = threadIdx.x;
    const int lane = t & 63, w = t >> 6;
    const int bg = w & 1, rr = (w >> 1) & 1, cb = (w >> 2) & 1;
    const int pidx = w >> 1;                   // exchange pair id (rr,cb)
    const int l31 = lane & 31, kg = lane >> 5;

    if (PASS == 2) {
        if (t < 128)      lser_sh[t] = lse_row[(size_t)n * LDIM + tM * 128 + t];
        else if (t < 256) lsec_sh[t - 128] = lse_col[(size_t)n * LDIM + tN * 128 + (t - 128)];
    }

    const i32x16 zero16 = {0,0,0,0,0,0,0,0,0,0,0,0,0,0,0,0};
    i32x16 accP = zero16, accQ = zero16;

    auto stage_step = [&](int s, int buf) {
        int q = s >> 2, kc = s & 3;
        int blkA = tM * 2 + (q >> 1);
        int blkB = tN * 2 + (q & 1);
        const char* gA = dig + DIG1_OFF + (((size_t)n * 64 + blkA) * 4 + kc) * 8192
                       + w * 1024 + lane * 16;
        const char* gB = dig + DIG2_OFF + (((size_t)n * 64 + blkB) * 4 + kc) * 8192
                       + w * 1024 + lane * 16;
        load_lds16(gA, sm + L_STAGE + buf * 8192 + w * 1024);
        load_lds16(gB, sm + L_STAGE + 16384 + buf * 8192 + w * 1024);
    };

    stage_step(0, 0);

    for (int s = 0; s < 16; ++s) {
        int q = s >> 2, kc = s & 3, buf = s & 1;
        int rq = q >> 1, cq = q & 1;
        __syncthreads();
        if (s < 15) stage_step(s + 1, (s + 1) & 1);

        const char* Ab = sm + L_STAGE + buf * 8192;
        const char* Bb = sm + L_STAGE + 16384 + buf * 8192;
        i32x4 aF[4], bF[4];
#pragma unroll
        for (int p = 0; p < 4; p++)
            aF[p] = *(const i32x4*)(Ab + (size_t)(p * 2048 + rr * 1024) + lane * 16);
#pragma unroll
        for (int p = 0; p < 4; p++)
            bF[p] = *(const i32x4*)(Bb + (size_t)(p * 2048 + cb * 1024) + lane * 16);

        if (bg == 0) {
            accP = mfma_i8(aF[0], bF[0], accP);                 // T0
            accQ = mfma_i8(aF[0], bF[3], accQ);                 // T3
            accQ = mfma_i8(aF[1], bF[2], accQ);
            accQ = mfma_i8(aF[2], bF[1], accQ);
            accQ = mfma_i8(aF[3], bF[0], accQ);
        } else {
            accP = mfma_i8(aF[0], bF[1], accP);                 // T1
            accP = mfma_i8(aF[1], bF[0], accP);
            accQ = mfma_i8(aF[0], bF[2], accQ);                 // T2
            accQ = mfma_i8(aF[1], bF[1], accQ);
            accQ = mfma_i8(aF[2], bF[0], accQ);
        }

        if (kc == 3) {
            // ---------- quadrant epilogue ----------
            char* X = sm + L_TR + pidx * 8192;
            // exchange: bg0 gives (T0,T3)[r 8..16), bg1 gives (T1,T2)[r 0..8)
            if (bg == 0) {
#pragma unroll
                for (int er = 0; er < 8; er++) {
                    *(int*)(X + er * 256 + lane * 4)        = accP[er + 8];
                    *(int*)(X + 2048 + er * 256 + lane * 4) = accQ[er + 8];
                }
            } else {
#pragma unroll
                for (int er = 0; er < 8; er++) {
                    *(int*)(X + 4096 + er * 256 + lane * 4) = accP[er];
                    *(int*)(X + 6144 + er * 256 + lane * 4) = accQ[er];
                }
            }
            __syncthreads();
            int T0v[8], T1v[8], T2v[8], T3v[8];
            int r_base;
            if (bg == 0) {
                r_base = 0;
#pragma unroll
                for (int er = 0; er < 8; er++) {
                    T1v[er] = *(const int*)(X + 4096 + er * 256 + lane * 4);
                    T2v[er] = *(const int*)(X + 6144 + er * 256 + lane * 4);
                    T0v[er] = accP[er];
                    T3v[er] = accQ[er];
                }
            } else {
                r_base = 8;
#pragma unroll
                for (int er = 0; er < 8; er++) {
                    T0v[er] = *(const int*)(X + er * 256 + lane * 4);
                    T3v[er] = *(const int*)(X + 2048 + er * 256 + lane * 4);
                    T1v[er] = accP[er + 8];
                    T2v[er] = accQ[er + 8];
                }
            }
            accP = zero16; accQ = zero16;
            __syncthreads();   // exchange reads done; TR region reusable

            double lam[8];
            int qr[8];
            const int qc = cb * 32 + l31;
#pragma unroll
            for (int er = 0; er < 8; er++) {
                int t01 = T0v[er] * 128 + T1v[er];
                int t23 = T2v[er] * 128 + T3v[er];
                lam[er] = (double)t01 * TEN_P15 + (double)t23 * TEN_P29;
                qr[er] = rr * 32 + CROW(r_base + er, kg);
            }
            const int contrib = rr * 4 + bg * 2 + kg;

            if (PASS == 1) {
                // col partial (local 8 rows), fp32 skeleton as before
                float cmax = -3.4e38f;
#pragma unroll
                for (int er = 0; er < 8; er++) cmax = fmaxf(cmax, (float)lam[er]);
                float cs = 0.f;
#pragma unroll
                for (int er = 0; er < 8; er++) cs += expf((float)(lam[er] - (double)cmax));
                *(float2*)(sm + L_CSTAT + (contrib * 64 + qc) * 8) = make_float2(cmax, cs);
                // transpose-write lam
#pragma unroll
                for (int er = 0; er < 8; er++)
                    *(double*)(sm + L_TR + ((size_t)qr[er] * 66 + qc) * 8) = lam[er];
                __syncthreads();
                // row stats: 8 lanes per row
                {
                    int gr = t >> 3, cofs = t & 7;
                    double v[8];
#pragma unroll
                    for (int j = 0; j < 8; j++)
                        v[j] = *(const double*)(sm + L_TR + ((size_t)gr * 66 + cofs + 8 * j) * 8);
                    double rmx = v[0];
#pragma unroll
                    for (int j = 1; j < 8; j++) rmx = fmax(rmx, v[j]);
                    rmx = fmax(rmx, __shfl_xor(rmx, 1));
                    rmx = fmax(rmx, __shfl_xor(rmx, 2));
                    rmx = fmax(rmx, __shfl_xor(rmx, 4));
                    float rmf = (float)rmx;
                    float rs = 0.f;
#pragma unroll
                    for (int j = 0; j < 8; j++) rs += expf((float)(v[j] - (double)rmf));
                    rs += __shfl_xor(rs, 1);
                    rs += __shfl_xor(rs, 2);
                    rs += __shfl_xor(rs, 4);
                    if (cofs == 0) {
                        float2* RR = (float2*)(sm + L_RRUN);
                        if (cq == 0) RR[gr] = make_float2(rmf, rs);
                        else {
                            float2 p = RR[gr];
                            float F = fmaxf(rmf, p.x);
                            float FS = rs * expf(rmf - F) + p.y * expf(p.x - F);
                            rowpart[((size_t)n * LDIM + tM * 128 + rq * 64 + gr) * 32 + tN] =
                                make_float2(F, FS);
                        }
                    }
                }
                if (t < 64) {   // col merge across 8 contribs
                    float2 p0 = *(const float2*)(sm + L_CSTAT + t * 8);
                    float M = p0.x;
#pragma unroll
                    for (int i = 1; i < 8; i++)
                        M = fmaxf(M, ((const float2*)(sm + L_CSTAT + (i * 64 + t) * 8))->x);
                    float S = 0.f;
#pragma unroll
                    for (int i = 0; i < 8; i++) {
                        float2 p = *(const float2*)(sm + L_CSTAT + (i * 64 + t) * 8);
                        S += p.y * expf(p.x - M);
                    }
                    float2* CR = (float2*)(sm + L_CRUN);
                    if (rq == 0) CR[cq * 64 + t] = make_float2(M, S);
                    else {
                        float2 p = CR[cq * 64 + t];
                        float F = fmaxf(M, p.x);
                        float FS = S * expf(M - F) + p.y * expf(p.x - F);
                        colpart[((size_t)n * LDIM + tN * 128 + cq * 64 + t) * 32 + tM] =
                            make_float2(F, FS);
                    }
                }
            } else {
                // PASS 2: keys
                u64 ck = 0ull;
                u64 rk[8];
#pragma unroll
                for (int er = 0; er < 8; er++) {
                    int rowt = rq * 64 + qr[er];
                    int colt = cq * 64 + qc;
                    float gf = (float)(2.0 * lam[er] - lser_sh[rowt] - lsec_sh[colt]);
                    u64 key = ((u64)fkey(gf)) << 32;
                    rk[er] = key | (uint32)(~(uint32)(tN * 128 + colt));
                    ck = umax64(ck, key | (uint32)(~(uint32)(tM * 128 + rowt)));
                }
                *(u64*)(sm + L_CSTAT + (contrib * 64 + qc) * 8) = ck;
#pragma unroll
                for (int er = 0; er < 8; er++)
                    *(u64*)(sm + L_TR + ((size_t)qr[er] * 66 + qc) * 8) = rk[er];
                __syncthreads();
                {
                    int gr = t >> 3, cofs = t & 7;
                    u64 b = 0ull;
#pragma unroll
                    for (int j = 0; j < 8; j++)
                        b = umax64(b, *(const u64*)(sm + L_TR + ((size_t)gr * 66 + cofs + 8 * j) * 8));
                    b = umax64(b, __shfl_xor(b, 1));
                    b = umax64(b, __shfl_xor(b, 2));
                    b = umax64(b, __shfl_xor(b, 4));
                    if (cofs == 0) {
                        u64* RR = (u64*)(sm + L_RRUN);
                        if (cq == 0) RR[gr] = b;
                        else atomicMax(&rowpack[(size_t)n * LDIM + tM * 128 + rq * 64 + gr],
                                       umax64(b, RR[gr]));
                    }
                }
                if (t < 64) {
                    u64 m = 0ull;
#pragma unroll
                    for (int i = 0; i < 8; i++)
                        m = umax64(m, *(const u64*)(sm + L_CSTAT + (i * 64 + t) * 8));
                    u64* CR = (u64*)(sm + L_CRUN);
                    if (rq == 0) CR[cq * 64 + t] = m;
                    else atomicMax(&colpack[(size_t)n * LDIM + tN * 128 + cq * 64 + t],
                                   umax64(m, CR[cq * 64 + t]));
                }
            }
        }
    }
}

__global__ __launch_bounds__(256) void merge_kernel(
    const float2* __restrict__ rowpart, const float2* __restrict__ colpart,
    double* __restrict__ lse_row, double* __restrict__ lse_col)
{
    int idx = blockIdx.x * 256 + threadIdx.x;
    const float2* src = (idx < BATCH * LDIM) ? rowpart : colpart;
    double* dst = (idx < BATCH * LDIM) ? lse_row : lse_col;
    int i = idx & (BATCH * LDIM - 1);
    double M = -1e300;
#pragma unroll
    for (int j = 0; j < 32; j++) M = fmax(M, (double)src[(size_t)i * 32 + j].x);
    double S = 0.0;
#pragma unroll
    for (int j = 0; j < 32; j++) {
        float2 ms = src[(size_t)i * 32 + j];
        S += (double)ms.y * exp((double)ms.x - M);
    }
    dst[i] = M + log(S);
}

__global__ __launch_bounds__(256) void out_kernel(
    const float* __restrict__ f1, const float* __restrict__ f2,
    const u64* __restrict__ rowpack, const u64* __restrict__ colpack,
    float* __restrict__ out)
{
    int n = blockIdx.y;
    int l0 = blockIdx.x * 64;
    int t = threadIdx.x;
    __shared__ int s_sh[64];
    __shared__ int m_sh[64];
    __shared__ float tile[64][129];
    if (t < 64) {
        u64 rp = rowpack[(size_t)n * LDIM + l0 + t];
        uint32 skey = (uint32)(rp >> 32);
        uint32 s = (~(uint32)rp) & 4095u;
        u64 cp = colpack[(size_t)n * LDIM + s];
        double g = (double)keyf(skey);
        int match = (((uint32)(cp >> 32)) == skey) && (exp(g) > 0.2);
        s_sh[t] = (int)s;
        m_sh[t] = match;
    }
    __syncthreads();
#pragma unroll
    for (int i = 0; i < 32; i++) {
        int idx = i * 256 + t;
        int lloc = idx >> 7, ch = idx & 127;
        float v = f1[((size_t)n * LDIM + l0 + lloc) * CDIM + ch];
        if (m_sh[lloc]) v -= f2[((size_t)n * LDIM + s_sh[lloc]) * CDIM + ch];
        tile[lloc][ch] = v;
    }
    __syncthreads();
#pragma unroll
    for (int i = 0; i < 32; i++) {
        int ch = i * 4 + (t >> 6), lw = t & 63;
        out[((size_t)n * CDIM + ch) * LDIM + l0 + lw] = tile[lw][ch];
    }
}

extern "C" void kernel_launch(void* const* d_in, const int* in_sizes, int n_in,
                              void* d_out, int out_size, void* d_ws, size_t ws_size,
                              hipStream_t stream)
{
    const float* f1 = (const float*)d_in[0];
    const float* f2 = (const float*)d_in[1];
    float* out = (float*)d_out;

    if (ws_size < WS_NEEDED) {
        fill_sentinel<<<(out_size + 255) / 256, 256, 0, stream>>>(out, out_size);
        return;
    }

    char* ws = (char*)d_ws;
    char* dig = ws;
    float2* rowpart = (float2*)(ws + ROWPART_OFF);
    float2* colpart = (float2*)(ws + COLPART_OFF);
    double* lse_row = (double*)(ws + LSER_OFF);
    double* lse_col = (double*)(ws + LSEC_OFF);
    u64* rowpack = (u64*)(ws + RPACK_OFF);
    u64* colpack = (u64*)(ws + CPACK_OFF);

    quant_kernel<<<dim3(2048), dim3(256), 0, stream>>>(f1, f2, dig);
    init_packs<<<dim3(128), dim3(256), 0, stream>>>(rowpack, colpack);
    gemm_kernel<1><<<dim3(8192), dim3(512), 0, stream>>>(
        dig, rowpart, colpart, lse_row, lse_col, rowpack, colpack);
    merge_kernel<<<dim3(256), dim3(256), 0, stream>>>(rowpart, colpart, lse_row, lse_col);
    gemm_kernel<2><<<dim3(8192), dim3(512), 0, stream>>>(
        dig, rowpart, colpart, lse_row, lse_col, rowpack, colpack);
    out_kernel<<<dim3(LDIM / 64, BATCH), dim3(256), 0, stream>>>(
        f1, f2, rowpack, colpack, out);
}

// Round 5
// 803.165 us; speedup vs baseline: 6.2983x; 1.0024x over previous
//
#include <hip/hip_runtime.h>
#include <stdint.h>

typedef unsigned int uint32;
typedef unsigned long long u64;

#define BATCH 8
#define LDIM 4096
#define CDIM 128

typedef __attribute__((ext_vector_type(4))) int i32x4;
typedef __attribute__((ext_vector_type(16))) int i32x16;

// ---- shared: digit planes ----
#define DIG1_OFF    0ull
#define DIG2_OFF    16777216ull
// ---- fallback (round-4) layout ----
#define ROWPART_OFF 33554432ull
#define COLPART_OFF 41943040ull
#define LSER_OFF    50331648ull
#define LSEC_OFF    50593792ull
#define RPACK_OFF   50855936ull
#define CPACK_OFF   51118080ull
#define WS_FALLBACK 51380224ull
// ---- new path: 2-batch matrix chunks ----
#define MAT_OFF     33554432ull
#define MATBYTES    268435456ull               /* 2 x 4096^2 x 8B */
#define CP_OFF      (MAT_OFF + MATBYTES)       /* colpart/colkeypart alias, 8MB */
#define NLROW_OFF   (CP_OFF + 8388608ull)      /* double[8][4096] */
#define NLCOL_OFF   (NLROW_OFF + 262144ull)
#define NRP_OFF     (NLCOL_OFF + 262144ull)    /* u64[8][4096] */
#define NCP_OFF     (NRP_OFF + 262144ull)
#define WS_NEW      (NCP_OFF + 262144ull)      /* ~297 MB */

#define TEN_P15 3.0517578125e-04
#define TEN_P29 1.862645149230957e-08

#define CROW(r, kgv) (((r)&3) + 8*((r)>>2) + 4*(kgv))

__device__ __forceinline__ uint32 fkey(float f) {
    uint32 u = __float_as_uint(f);
    return (u & 0x80000000u) ? ~u : (u | 0x80000000u);
}
__device__ __forceinline__ float keyf(uint32 k) {
    uint32 u = (k & 0x80000000u) ? (k ^ 0x80000000u) : ~k;
    return __uint_as_float(u);
}
__device__ __forceinline__ i32x16 mfma_i8(i32x4 a, i32x4 b, i32x16 c) {
    return __builtin_amdgcn_mfma_i32_32x32x32_i8(a, b, c, 0, 0, 0);
}
__device__ __forceinline__ void load_lds16(const char* g, char* l) {
    __builtin_amdgcn_global_load_lds((__attribute__((address_space(1))) void*)(g),
                                     (__attribute__((address_space(3))) void*)(l), 16, 0, 0);
}
__device__ __forceinline__ u64 umax64(u64 a, u64 b) { return a > b ? a : b; }

__global__ void fill_sentinel(float* out, int nelem) {
    int i = blockIdx.x * 256 + threadIdx.x;
    if (i < nelem) out[i] = 12345.0f;
}

__global__ void init_packs(u64* __restrict__ rowpack, u64* __restrict__ colpack) {
    int idx = blockIdx.x * 256 + threadIdx.x;
    if (idx < BATCH * LDIM) { rowpack[idx] = 0ull; colpack[idx] = 0ull; }
}

// Quantize fp32 -> 4 exact base-128 signed digits of round(x*2^25).
__global__ __launch_bounds__(256) void quant_kernel(const float* __restrict__ f1,
                                                    const float* __restrict__ f2,
                                                    char* __restrict__ dig)
{
    int tid = blockIdx.x * 256 + threadIdx.x;
    int l31 = tid & 31;
    int kg  = (tid >> 5) & 1;
    int kc  = (tid >> 6) & 3;
    int rb  = (tid >> 8) & 1;
    int blk = (tid >> 9) & 63;
    int n   = (tid >> 15) & 7;
    int inp = tid >> 18;
    int row = blk * 64 + rb * 32 + l31;

    const float* src = (inp ? f2 : f1) + ((size_t)(n * LDIM + row)) * CDIM + kc * 32 + kg * 16;
    char* dstc = dig + (inp ? DIG2_OFF : DIG1_OFF)
               + (((size_t)n * 64 + blk) * 4 + kc) * 8192;
    int gpos = rb * 64 + kg * 32 + l31;

    float4 v0 = ((const float4*)src)[0];
    float4 v1 = ((const float4*)src)[1];
    float4 v2 = ((const float4*)src)[2];
    float4 v3 = ((const float4*)src)[3];
    float xs[16] = {v0.x,v0.y,v0.z,v0.w, v1.x,v1.y,v1.z,v1.w,
                    v2.x,v2.y,v2.z,v2.w, v3.x,v3.y,v3.z,v3.w};
    uint32 wds[4][4] = {{0,0,0,0},{0,0,0,0},{0,0,0,0},{0,0,0,0}};
#pragma unroll
    for (int e = 0; e < 16; e++) {
        int q = __float2int_rn(xs[e] * 33554432.0f);
        int d0 = (q + (1 << 20)) >> 21; q -= d0 << 21;
        int d1 = (q + (1 << 13)) >> 14; q -= d1 << 14;
        int d2 = (q + (1 << 6)) >> 7;   q -= d2 << 7;
        int sh = (e & 3) * 8;
        wds[0][e >> 2] |= (uint32)(d0 & 255) << sh;
        wds[1][e >> 2] |= (uint32)(d1 & 255) << sh;
        wds[2][e >> 2] |= (uint32)(d2 & 255) << sh;
        wds[3][e >> 2] |= (uint32)(q  & 255) << sh;
    }
#pragma unroll
    for (int p = 0; p < 4; p++) {
        *(int4*)(dstc + (size_t)(p * 128 + gpos) * 16) =
            make_int4(wds[p][0], wds[p][1], wds[p][2], wds[p][3]);
    }
}

// =====================  NEW PATH  =====================

// Stripped GEMM: exact i8-digit products, bank exchange, store (t01,t23) int2.
__global__ __launch_bounds__(512, 4) void gemm_store(
    const char* __restrict__ dig, int n0, int2* __restrict__ mat)
{
    __shared__ __align__(16) char sm[65536];   // 32KB stage + 32KB exchange
    int wg = blockIdx.x;                       // 2048 blocks
    int swz = (wg & 7) * 256 + (wg >> 3);
    int nl = swz >> 10;                        // chunk-local batch 0..1
    int n  = n0 + nl;
    int tM = (swz >> 5) & 31;
    int tN = swz & 31;

    const int t = threadIdx.x;
    const int lane = t & 63, w = t >> 6;
    const int bg = w & 1, rr = (w >> 1) & 1, cb = (w >> 2) & 1;
    const int pidx = w >> 1;
    const int l31 = lane & 31, kg = lane >> 5;

    const i32x16 zero16 = {0,0,0,0,0,0,0,0,0,0,0,0,0,0,0,0};
    i32x16 accP = zero16, accQ = zero16;

    auto stage_step = [&](int s, int buf) {
        int q = s >> 2, kc = s & 3;
        int blkA = tM * 2 + (q >> 1);
        int blkB = tN * 2 + (q & 1);
        const char* gA = dig + DIG1_OFF + (((size_t)n * 64 + blkA) * 4 + kc) * 8192
                       + w * 1024 + lane * 16;
        const char* gB = dig + DIG2_OFF + (((size_t)n * 64 + blkB) * 4 + kc) * 8192
                       + w * 1024 + lane * 16;
        load_lds16(gA, sm + buf * 8192 + w * 1024);
        load_lds16(gB, sm + 16384 + buf * 8192 + w * 1024);
    };

    stage_step(0, 0);

    for (int s = 0; s < 16; ++s) {
        int q = s >> 2, kc = s & 3, buf = s & 1;
        int rq = q >> 1, cq = q & 1;
        __syncthreads();
        if (s < 15) stage_step(s + 1, (s + 1) & 1);

        const char* Ab = sm + buf * 8192;
        const char* Bb = sm + 16384 + buf * 8192;
        i32x4 aF[4], bF[4];
#pragma unroll
        for (int p = 0; p < 4; p++)
            aF[p] = *(const i32x4*)(Ab + (size_t)(p * 2048 + rr * 1024) + lane * 16);
#pragma unroll
        for (int p = 0; p < 4; p++)
            bF[p] = *(const i32x4*)(Bb + (size_t)(p * 2048 + cb * 1024) + lane * 16);

        if (bg == 0) {
            accP = mfma_i8(aF[0], bF[0], accP);                 // T0
            accQ = mfma_i8(aF[0], bF[3], accQ);                 // T3
            accQ = mfma_i8(aF[1], bF[2], accQ);
            accQ = mfma_i8(aF[2], bF[1], accQ);
            accQ = mfma_i8(aF[3], bF[0], accQ);
        } else {
            accP = mfma_i8(aF[0], bF[1], accP);                 // T1
            accP = mfma_i8(aF[1], bF[0], accP);
            accQ = mfma_i8(aF[0], bF[2], accQ);                 // T2
            accQ = mfma_i8(aF[1], bF[1], accQ);
            accQ = mfma_i8(aF[2], bF[0], accQ);
        }

        if (kc == 3) {
            char* X = sm + 32768 + pidx * 8192;
            if (bg == 0) {
#pragma unroll
                for (int er = 0; er < 8; er++) {
                    *(int*)(X + er * 256 + lane * 4)        = accP[er + 8];
                    *(int*)(X + 2048 + er * 256 + lane * 4) = accQ[er + 8];
                }
            } else {
#pragma unroll
                for (int er = 0; er < 8; er++) {
                    *(int*)(X + 4096 + er * 256 + lane * 4) = accP[er];
                    *(int*)(X + 6144 + er * 256 + lane * 4) = accQ[er];
                }
            }
            __syncthreads();
            int T0v[8], T1v[8], T2v[8], T3v[8];
            int r_base;
            if (bg == 0) {
                r_base = 0;
#pragma unroll
                for (int er = 0; er < 8; er++) {
                    T1v[er] = *(const int*)(X + 4096 + er * 256 + lane * 4);
                    T2v[er] = *(const int*)(X + 6144 + er * 256 + lane * 4);
                    T0v[er] = accP[er];
                    T3v[er] = accQ[er];
                }
            } else {
                r_base = 8;
#pragma unroll
                for (int er = 0; er < 8; er++) {
                    T0v[er] = *(const int*)(X + er * 256 + lane * 4);
                    T3v[er] = *(const int*)(X + 2048 + er * 256 + lane * 4);
                    T1v[er] = accP[er + 8];
                    T2v[er] = accQ[er + 8];
                }
            }
            accP = zero16; accQ = zero16;
            // store: 8 coalesced int2 per lane
            int qc = cb * 32 + l31;
            int2* mbase = mat + ((size_t)nl * LDIM + tM * 128 + rq * 64) * LDIM
                        + tN * 128 + cq * 64 + qc;
#pragma unroll
            for (int er = 0; er < 8; er++) {
                int qr = rr * 32 + CROW(r_base + er, kg);
                int t01 = T0v[er] * 128 + T1v[er];
                int t23 = T2v[er] * 128 + T3v[er];
                mbase[(size_t)qr * LDIM] = make_int2(t01, t23);
            }
        }
    }
}

// Reader 1: stream matrix chunk -> row LSE (direct) + col partials.
__global__ __launch_bounds__(512) void stats_kernel(
    const int2* __restrict__ mat, int n0,
    double* __restrict__ lse_row, float2* __restrict__ colpart)
{
    __shared__ double lam[32][130];
    __shared__ float2 cpart[4][128];
    int b = blockIdx.x;                 // 256
    int nl = b >> 7, rc = b & 127;
    int r0 = rc * 32;
    int t = threadIdx.x;
    const int rw = t >> 4, cofs = t & 15;
    double M = -1e300, S = 0.0;
    const int2* msrc = mat + ((size_t)nl * LDIM + r0) * LDIM;

    for (int cc = 0; cc < 32; cc++) {
        __syncthreads();
#pragma unroll
        for (int i = 0; i < 4; i++) {
            int e2 = t + 512 * i;
            int r = e2 >> 6, c = (e2 & 63) * 2;
            int4 v = *(const int4*)(msrc + (size_t)r * LDIM + cc * 128 + c);
            lam[r][c]     = (double)v.x * TEN_P15 + (double)v.y * TEN_P29;
            lam[r][c + 1] = (double)v.z * TEN_P15 + (double)v.w * TEN_P29;
        }
        __syncthreads();
        // row phase: 8 cols per thread, streaming (M,S)
#pragma unroll
        for (int j = 0; j < 8; j++) {
            double v = lam[rw][cofs + 16 * j];
            if (v > M) { S = S * (double)expf((float)(M - v)) + 1.0; M = v; }
            else S += (double)expf((float)(v - M));
        }
        // col phase: 8 rows per thread
        {
            int c = t & 127, qtr = t >> 7;
            double cm = -1e300, cs = 0.0;
#pragma unroll
            for (int i = 0; i < 8; i++) {
                double v = lam[qtr * 8 + i][c];
                if (v > cm) { cs = cs * (double)expf((float)(cm - v)) + 1.0; cm = v; }
                else cs += (double)expf((float)(v - cm));
            }
            float cmf = (float)cm;
            float csf = (float)(cs * (double)expf((float)(cm - (double)cmf)));
            cpart[qtr][c] = make_float2(cmf, csf);
        }
        __syncthreads();
        if (t < 128) {
            float M4 = cpart[0][t].x;
#pragma unroll
            for (int i = 1; i < 4; i++) M4 = fmaxf(M4, cpart[i][t].x);
            float S4 = 0.f;
#pragma unroll
            for (int i = 0; i < 4; i++) S4 += cpart[i][t].y * expf(cpart[i][t].x - M4);
            colpart[((size_t)nl * 128 + rc) * 4096 + cc * 128 + t] = make_float2(M4, S4);
        }
    }
#pragma unroll
    for (int m = 1; m < 16; m <<= 1) {
        double om = __shfl_xor(M, m);
        double os = __shfl_xor(S, m);
        double nm = fmax(M, om);
        S = S * (double)expf((float)(M - nm)) + os * (double)expf((float)(om - nm));
        M = nm;
    }
    if (cofs == 0) lse_row[(size_t)(n0 + nl) * LDIM + r0 + rw] = M + log(S);
}

__global__ __launch_bounds__(256) void lsec_merge(
    const float2* __restrict__ colpart, int n0, double* __restrict__ lse_col)
{
    int idx = blockIdx.x * 256 + threadIdx.x;   // 0..8191
    int nl = idx >> 12, col = idx & 4095;
    const float2* p = colpart + (size_t)nl * 128 * 4096 + col;
    double M = -1e300;
#pragma unroll 4
    for (int rc = 0; rc < 128; rc++) M = fmax(M, (double)p[(size_t)rc * 4096].x);
    double S = 0.0;
#pragma unroll 4
    for (int rc = 0; rc < 128; rc++) {
        float2 ms = p[(size_t)rc * 4096];
        S += (double)ms.y * exp((double)ms.x - M);
    }
    lse_col[(size_t)(n0 + nl) * LDIM + col] = M + log(S);
}

// Reader 2: stream matrix chunk -> packed argmax keys. gf computed ONCE per
// element, used for both row and col packing -> exact mutual equality.
__global__ __launch_bounds__(512) void keys_kernel(
    const int2* __restrict__ mat, int n0,
    const double* __restrict__ lse_row, const double* __restrict__ lse_col,
    u64* __restrict__ rowpack, u64* __restrict__ colkeypart)
{
    __shared__ double lam2[32][130];
    __shared__ double lsec_sh[128];
    __shared__ double lser_sh[32];
    __shared__ u64 kpart[4][128];
    int b = blockIdx.x;
    int nl = b >> 7, rc = b & 127;
    int r0 = rc * 32;
    int t = threadIdx.x;
    if (t < 32) lser_sh[t] = lse_row[(size_t)(n0 + nl) * LDIM + r0 + t];
    const int rw = t >> 4, cofs = t & 15;
    u64 rbest = 0ull;
    const int2* msrc = mat + ((size_t)nl * LDIM + r0) * LDIM;

    for (int cc = 0; cc < 32; cc++) {
        __syncthreads();
        if (t < 128) lsec_sh[t] = lse_col[(size_t)(n0 + nl) * LDIM + cc * 128 + t];
#pragma unroll
        for (int i = 0; i < 4; i++) {
            int e2 = t + 512 * i;
            int r = e2 >> 6, c = (e2 & 63) * 2;
            int4 v = *(const int4*)(msrc + (size_t)r * LDIM + cc * 128 + c);
            lam2[r][c]     = (double)v.x * (2.0 * TEN_P15) + (double)v.y * (2.0 * TEN_P29);
            lam2[r][c + 1] = (double)v.z * (2.0 * TEN_P15) + (double)v.w * (2.0 * TEN_P29);
        }
        __syncthreads();
        {
            double lr = lser_sh[rw];
#pragma unroll
            for (int j = 0; j < 8; j++) {
                int c = cofs + 16 * j;
                float gf = (float)((lam2[rw][c] - lr) - lsec_sh[c]);
                u64 key = (((u64)fkey(gf)) << 32) | (uint32)(~(uint32)(cc * 128 + c));
                rbest = umax64(rbest, key);
            }
        }
        {
            int c = t & 127, qtr = t >> 7;
            double lc = lsec_sh[c];
            u64 cbest = 0ull;
#pragma unroll
            for (int i = 0; i < 8; i++) {
                int r = qtr * 8 + i;
                float gf = (float)((lam2[r][c] - lser_sh[r]) - lc);
                u64 key = (((u64)fkey(gf)) << 32) | (uint32)(~(uint32)(r0 + r));
                cbest = umax64(cbest, key);
            }
            kpart[qtr][c] = cbest;
        }
        __syncthreads();
        if (t < 128) {
            u64 m = umax64(umax64(kpart[0][t], kpart[1][t]),
                           umax64(kpart[2][t], kpart[3][t]));
            colkeypart[((size_t)nl * 128 + rc) * 4096 + cc * 128 + t] = m;
        }
    }
#pragma unroll
    for (int m = 1; m < 16; m <<= 1) rbest = umax64(rbest, __shfl_xor(rbest, m));
    if (cofs == 0) rowpack[(size_t)(n0 + nl) * LDIM + r0 + rw] = rbest;
}

__global__ __launch_bounds__(256) void colkey_merge(
    const u64* __restrict__ colkeypart, int n0, u64* __restrict__ colpack)
{
    int idx = blockIdx.x * 256 + threadIdx.x;   // 0..8191
    int nl = idx >> 12, col = idx & 4095;
    const u64* p = colkeypart + (size_t)nl * 128 * 4096 + col;
    u64 m = 0ull;
#pragma unroll 4
    for (int rc = 0; rc < 128; rc++) m = umax64(m, p[(size_t)rc * 4096]);
    colpack[(size_t)(n0 + nl) * LDIM + col] = m;
}

// =====================  FALLBACK (round-4, verbatim)  =====================

#define L_STAGE   0
#define L_TR      32768
#define L_CSTAT   66560
#define L_RRUN    70656
#define L_CRUN    71168
#define L_LSER    72192
#define L_LSEC    73216
#define L_TOTAL   74240

template <int PASS>
__global__ __launch_bounds__(512, 4) void gemm_kernel(
    const char* __restrict__ dig,
    float2* __restrict__ rowpart, float2* __restrict__ colpart,
    const double* __restrict__ lse_row, const double* __restrict__ lse_col,
    u64* __restrict__ rowpack, u64* __restrict__ colpack)
{
    __shared__ __align__(16) char sm[L_TOTAL];
    double* lser_sh = (double*)(sm + L_LSER);
    double* lsec_sh = (double*)(sm + L_LSEC);

    int wg = blockIdx.x;
    int swz = (wg & 7) * 1024 + (wg >> 3);
    int n  = swz >> 10;
    int tM = (swz >> 5) & 31;
    int tN = swz & 31;

    const int t = threadIdx.x;
    const int lane = t & 63, w = t >> 6;
    const int bg = w & 1, rr = (w >> 1) & 1, cb = (w >> 2) & 1;
    const int pidx = w >> 1;
    const int l31 = lane & 31, kg = lane >> 5;

    if (PASS == 2) {
        if (t < 128)      lser_sh[t] = lse_row[(size_t)n * LDIM + tM * 128 + t];
        else if (t < 256) lsec_sh[t - 128] = lse_col[(size_t)n * LDIM + tN * 128 + (t - 128)];
    }

    const i32x16 zero16 = {0,0,0,0,0,0,0,0,0,0,0,0,0,0,0,0};
    i32x16 accP = zero16, accQ = zero16;

    auto stage_step = [&](int s, int buf) {
        int q = s >> 2, kc = s & 3;
        int blkA = tM * 2 + (q >> 1);
        int blkB = tN * 2 + (q & 1);
        const char* gA = dig + DIG1_OFF + (((size_t)n * 64 + blkA) * 4 + kc) * 8192
                       + w * 1024 + lane * 16;
        const char* gB = dig + DIG2_OFF + (((size_t)n * 64 + blkB) * 4 + kc) * 8192
                       + w * 1024 + lane * 16;
        load_lds16(gA, sm + L_STAGE + buf * 8192 + w * 1024);
        load_lds16(gB, sm + L_STAGE + 16384 + buf * 8192 + w * 1024);
    };

    stage_step(0, 0);

    for (int s = 0; s < 16; ++s) {
        int q = s >> 2, kc = s & 3, buf = s & 1;
        int rq = q >> 1, cq = q & 1;
        __syncthreads();
        if (s < 15) stage_step(s + 1, (s + 1) & 1);

        const char* Ab = sm + L_STAGE + buf * 8192;
        const char* Bb = sm + L_STAGE + 16384 + buf * 8192;
        i32x4 aF[4], bF[4];
#pragma unroll
        for (int p = 0; p < 4; p++)
            aF[p] = *(const i32x4*)(Ab + (size_t)(p * 2048 + rr * 1024) + lane * 16);
#pragma unroll
        for (int p = 0; p < 4; p++)
            bF[p] = *(const i32x4*)(Bb + (size_t)(p * 2048 + cb * 1024) + lane * 16);

        if (bg == 0) {
            accP = mfma_i8(aF[0], bF[0], accP);
            accQ = mfma_i8(aF[0], bF[3], accQ);
            accQ = mfma_i8(aF[1], bF[2], accQ);
            accQ = mfma_i8(aF[2], bF[1], accQ);
            accQ = mfma_i8(aF[3], bF[0], accQ);
        } else {
            accP = mfma_i8(aF[0], bF[1], accP);
            accP = mfma_i8(aF[1], bF[0], accP);
            accQ = mfma_i8(aF[0], bF[2], accQ);
            accQ = mfma_i8(aF[1], bF[1], accQ);
            accQ = mfma_i8(aF[2], bF[0], accQ);
        }

        if (kc == 3) {
            char* X = sm + L_TR + pidx * 8192;
            if (bg == 0) {
#pragma unroll
                for (int er = 0; er < 8; er++) {
                    *(int*)(X + er * 256 + lane * 4)        = accP[er + 8];
                    *(int*)(X + 2048 + er * 256 + lane * 4) = accQ[er + 8];
                }
            } else {
#pragma unroll
                for (int er = 0; er < 8; er++) {
                    *(int*)(X + 4096 + er * 256 + lane * 4) = accP[er];
                    *(int*)(X + 6144 + er * 256 + lane * 4) = accQ[er];
                }
            }
            __syncthreads();
            int T0v[8], T1v[8], T2v[8], T3v[8];
            int r_base;
            if (bg == 0) {
                r_base = 0;
#pragma unroll
                for (int er = 0; er < 8; er++) {
                    T1v[er] = *(const int*)(X + 4096 + er * 256 + lane * 4);
                    T2v[er] = *(const int*)(X + 6144 + er * 256 + lane * 4);
                    T0v[er] = accP[er];
                    T3v[er] = accQ[er];
                }
            } else {
                r_base = 8;
#pragma unroll
                for (int er = 0; er < 8; er++) {
                    T0v[er] = *(const int*)(X + er * 256 + lane * 4);
                    T3v[er] = *(const int*)(X + 2048 + er * 256 + lane * 4);
                    T1v[er] = accP[er + 8];
                    T2v[er] = accQ[er + 8];
                }
            }
            accP = zero16; accQ = zero16;
            __syncthreads();

            double lam[8];
            int qr[8];
            const int qc = cb * 32 + l31;
#pragma unroll
            for (int er = 0; er < 8; er++) {
                int t01 = T0v[er] * 128 + T1v[er];
                int t23 = T2v[er] * 128 + T3v[er];
                lam[er] = (double)t01 * TEN_P15 + (double)t23 * TEN_P29;
                qr[er] = rr * 32 + CROW(r_base + er, kg);
            }
            const int contrib = rr * 4 + bg * 2 + kg;

            if (PASS == 1) {
                float cmax = -3.4e38f;
#pragma unroll
                for (int er = 0; er < 8; er++) cmax = fmaxf(cmax, (float)lam[er]);
                float cs = 0.f;
#pragma unroll
                for (int er = 0; er < 8; er++) cs += expf((float)(lam[er] - (double)cmax));
                *(float2*)(sm + L_CSTAT + (contrib * 64 + qc) * 8) = make_float2(cmax, cs);
#pragma unroll
                for (int er = 0; er < 8; er++)
                    *(double*)(sm + L_TR + ((size_t)qr[er] * 66 + qc) * 8) = lam[er];
                __syncthreads();
                {
                    int gr = t >> 3, cofs = t & 7;
                    double v[8];
#pragma unroll
                    for (int j = 0; j < 8; j++)
                        v[j] = *(const double*)(sm + L_TR + ((size_t)gr * 66 + cofs + 8 * j) * 8);
                    double rmx = v[0];
#pragma unroll
                    for (int j = 1; j < 8; j++) rmx = fmax(rmx, v[j]);
                    rmx = fmax(rmx, __shfl_xor(rmx, 1));
                    rmx = fmax(rmx, __shfl_xor(rmx, 2));
                    rmx = fmax(rmx, __shfl_xor(rmx, 4));
                    float rmf = (float)rmx;
                    float rs = 0.f;
#pragma unroll
                    for (int j = 0; j < 8; j++) rs += expf((float)(v[j] - (double)rmf));
                    rs += __shfl_xor(rs, 1);
                    rs += __shfl_xor(rs, 2);
                    rs += __shfl_xor(rs, 4);
                    if (cofs == 0) {
                        float2* RR = (float2*)(sm + L_RRUN);
                        if (cq == 0) RR[gr] = make_float2(rmf, rs);
                        else {
                            float2 p = RR[gr];
                            float F = fmaxf(rmf, p.x);
                            float FS = rs * expf(rmf - F) + p.y * expf(p.x - F);
                            rowpart[((size_t)n * LDIM + tM * 128 + rq * 64 + gr) * 32 + tN] =
                                make_float2(F, FS);
                        }
                    }
                }
                if (t < 64) {
                    float2 p0 = *(const float2*)(sm + L_CSTAT + t * 8);
                    float M = p0.x;
#pragma unroll
                    for (int i = 1; i < 8; i++)
                        M = fmaxf(M, ((const float2*)(sm + L_CSTAT + (i * 64 + t) * 8))->x);
                    float S = 0.f;
#pragma unroll
                    for (int i = 0; i < 8; i++) {
                        float2 p = *(const float2*)(sm + L_CSTAT + (i * 64 + t) * 8);
                        S += p.y * expf(p.x - M);
                    }
                    float2* CR = (float2*)(sm + L_CRUN);
                    if (rq == 0) CR[cq * 64 + t] = make_float2(M, S);
                    else {
                        float2 p = CR[cq * 64 + t];
                        float F = fmaxf(M, p.x);
                        float FS = S * expf(M - F) + p.y * expf(p.x - F);
                        colpart[((size_t)n * LDIM + tN * 128 + cq * 64 + t) * 32 + tM] =
                            make_float2(F, FS);
                    }
                }
            } else {
                int colg = tN * 128 + cq * 64 + bg * 32 + l31;
                (void)colg;
                u64 ck = 0ull;
                u64 rk[8];
#pragma unroll
                for (int er = 0; er < 8; er++) {
                    int rowt = rq * 64 + qr[er];
                    int colt = cq * 64 + qc;
                    float gf = (float)(2.0 * lam[er] - lser_sh[rowt] - lsec_sh[colt]);
                    u64 key = ((u64)fkey(gf)) << 32;
                    rk[er] = key | (uint32)(~(uint32)(tN * 128 + colt));
                    ck = umax64(ck, key | (uint32)(~(uint32)(tM * 128 + rowt)));
                }
                *(u64*)(sm + L_CSTAT + (contrib * 64 + qc) * 8) = ck;
#pragma unroll
                for (int er = 0; er < 8; er++)
                    *(u64*)(sm + L_TR + ((size_t)qr[er] * 66 + qc) * 8) = rk[er];
                __syncthreads();
                {
                    int gr = t >> 3, cofs = t & 7;
                    u64 bb = 0ull;
#pragma unroll
                    for (int j = 0; j < 8; j++)
                        bb = umax64(bb, *(const u64*)(sm + L_TR + ((size_t)gr * 66 + cofs + 8 * j) * 8));
                    bb = umax64(bb, __shfl_xor(bb, 1));
                    bb = umax64(bb, __shfl_xor(bb, 2));
                    bb = umax64(bb, __shfl_xor(bb, 4));
                    if (cofs == 0) {
                        u64* RR = (u64*)(sm + L_RRUN);
                        if (cq == 0) RR[gr] = bb;
                        else atomicMax(&rowpack[(size_t)n * LDIM + tM * 128 + rq * 64 + gr],
                                       umax64(bb, RR[gr]));
                    }
                }
                if (t < 64) {
                    u64 m = 0ull;
#pragma unroll
                    for (int i = 0; i < 8; i++)
                        m = umax64(m, *(const u64*)(sm + L_CSTAT + (i * 64 + t) * 8));
                    u64* CR = (u64*)(sm + L_CRUN);
                    if (rq == 0) CR[cq * 64 + t] = m;
                    else atomicMax(&colpack[(size_t)n * LDIM + tN * 128 + cq * 64 + t],
                                   umax64(m, CR[cq * 64 + t]));
                }
            }
        }
    }
}

__global__ __launch_bounds__(256) void merge_kernel(
    const float2* __restrict__ rowpart, const float2* __restrict__ colpart,
    double* __restrict__ lse_row, double* __restrict__ lse_col)
{
    int idx = blockIdx.x * 256 + threadIdx.x;
    const float2* src = (idx < BATCH * LDIM) ? rowpart : colpart;
    double* dst = (idx < BATCH * LDIM) ? lse_row : lse_col;
    int i = idx & (BATCH * LDIM - 1);
    double M = -1e300;
#pragma unroll
    for (int j = 0; j < 32; j++) M = fmax(M, (double)src[(size_t)i * 32 + j].x);
    double S = 0.0;
#pragma unroll
    for (int j = 0; j < 32; j++) {
        float2 ms = src[(size_t)i * 32 + j];
        S += (double)ms.y * exp((double)ms.x - M);
    }
    dst[i] = M + log(S);
}

// =====================  OUTPUT  =====================

__global__ __launch_bounds__(256) void out_kernel(
    const float* __restrict__ f1, const float* __restrict__ f2,
    const u64* __restrict__ rowpack, const u64* __restrict__ colpack,
    float* __restrict__ out)
{
    int n = blockIdx.y;
    int l0 = blockIdx.x * 64;
    int t = threadIdx.x;
    __shared__ int s_sh[64];
    __shared__ int m_sh[64];
    __shared__ float tile[64][129];
    if (t < 64) {
        u64 rp = rowpack[(size_t)n * LDIM + l0 + t];
        uint32 skey = (uint32)(rp >> 32);
        uint32 s = (~(uint32)rp) & 4095u;
        u64 cp = colpack[(size_t)n * LDIM + s];
        double g = (double)keyf(skey);
        int match = (((uint32)(cp >> 32)) == skey) && (exp(g) > 0.2);
        s_sh[t] = (int)s;
        m_sh[t] = match;
    }
    __syncthreads();
#pragma unroll
    for (int i = 0; i < 32; i++) {
        int idx = i * 256 + t;
        int lloc = idx >> 7, ch = idx & 127;
        float v = f1[((size_t)n * LDIM + l0 + lloc) * CDIM + ch];
        if (m_sh[lloc]) v -= f2[((size_t)n * LDIM + s_sh[lloc]) * CDIM + ch];
        tile[lloc][ch] = v;
    }
    __syncthreads();
#pragma unroll
    for (int i = 0; i < 32; i++) {
        int ch = i * 4 + (t >> 6), lw = t & 63;
        out[((size_t)n * CDIM + ch) * LDIM + l0 + lw] = tile[lw][ch];
    }
}

extern "C" void kernel_launch(void* const* d_in, const int* in_sizes, int n_in,
                              void* d_out, int out_size, void* d_ws, size_t ws_size,
                              hipStream_t stream)
{
    const float* f1 = (const float*)d_in[0];
    const float* f2 = (const float*)d_in[1];
    float* out = (float*)d_out;
    char* ws = (char*)d_ws;
    char* dig = ws;

    if (ws_size >= WS_NEW) {
        int2* mat        = (int2*)(ws + MAT_OFF);
        float2* colpart  = (float2*)(ws + CP_OFF);
        u64* colkeypart  = (u64*)(ws + CP_OFF);
        double* lse_row  = (double*)(ws + NLROW_OFF);
        double* lse_col  = (double*)(ws + NLCOL_OFF);
        u64* rowpack     = (u64*)(ws + NRP_OFF);
        u64* colpack     = (u64*)(ws + NCP_OFF);

        quant_kernel<<<dim3(2048), dim3(256), 0, stream>>>(f1, f2, dig);
        for (int n0 = 0; n0 < BATCH; n0 += 2) {
            gemm_store<<<dim3(2048), dim3(512), 0, stream>>>(dig, n0, mat);
            stats_kernel<<<dim3(256), dim3(512), 0, stream>>>(mat, n0, lse_row, colpart);
            lsec_merge<<<dim3(32), dim3(256), 0, stream>>>(colpart, n0, lse_col);
            keys_kernel<<<dim3(256), dim3(512), 0, stream>>>(mat, n0, lse_row, lse_col,
                                                             rowpack, colkeypart);
            colkey_merge<<<dim3(32), dim3(256), 0, stream>>>(colkeypart, n0, colpack);
        }
        out_kernel<<<dim3(LDIM / 64, BATCH), dim3(256), 0, stream>>>(
            f1, f2, rowpack, colpack, out);
    } else if (ws_size >= WS_FALLBACK) {
        float2* rowpart = (float2*)(ws + ROWPART_OFF);
        float2* colpart = (float2*)(ws + COLPART_OFF);
        double* lse_row = (double*)(ws + LSER_OFF);
        double* lse_col = (double*)(ws + LSEC_OFF);
        u64* rowpack = (u64*)(ws + RPACK_OFF);
        u64* colpack = (u64*)(ws + CPACK_OFF);

        quant_kernel<<<dim3(2048), dim3(256), 0, stream>>>(f1, f2, dig);
        init_packs<<<dim3(128), dim3(256), 0, stream>>>(rowpack, colpack);
        gemm_kernel<1><<<dim3(8192), dim3(512), 0, stream>>>(
            dig, rowpart, colpart, lse_row, lse_col, rowpack, colpack);
        merge_kernel<<<dim3(256), dim3(256), 0, stream>>>(rowpart, colpart, lse_row, lse_col);
        gemm_kernel<2><<<dim3(8192), dim3(512), 0, stream>>>(
            dig, rowpart, colpart, lse_row, lse_col, rowpack, colpack);
        out_kernel<<<dim3(LDIM / 64, BATCH), dim3(256), 0, stream>>>(
            f1, f2, rowpack, colpack, out);
    } else {
        fill_sentinel<<<(out_size + 255) / 256, 256, 0, stream>>>(out, out_size);
    }
}

// Round 6
// 726.461 us; speedup vs baseline: 6.9633x; 1.1056x over previous
//
#include <hip/hip_runtime.h>
#include <stdint.h>

typedef unsigned int uint32;
typedef unsigned long long u64;

#define BATCH 8
#define LDIM 4096
#define CDIM 128

typedef __attribute__((ext_vector_type(4))) int i32x4;
typedef __attribute__((ext_vector_type(16))) int i32x16;

// ---- workspace layout (bytes) ----
#define DIG1_OFF    0ull          /* i8 digits f1, LDS-order: 16 MB */
#define DIG2_OFF    16777216ull   /* i8 digits f2 */
#define ROWPART_OFF 33554432ull   /* float2 [8][4096][32] = 8 MB */
#define COLPART_OFF 41943040ull   /* float2 [8][4096][32] = 8 MB */
#define LSER_OFF    50331648ull   /* double [8][4096] */
#define LSEC_OFF    50593792ull
#define RPACK_OFF   50855936ull   /* u64 [8][4096] */
#define CPACK_OFF   51118080ull
#define WS_NEEDED   51380224ull

// lam2 = log2(e) * 10 * (t01*2^-15 + t23*2^-29)  (log2-domain logits)
#define C1L (3.0517578125e-04 * 1.4426950408889634)
#define C2L (1.862645149230957e-08 * 1.4426950408889634)
#define LOG2_02 (-2.3219280948873623)   /* log2(0.2) */

#define CROW(r, kgv) (((r)&3) + 8*((r)>>2) + 4*(kgv))

// ---- LDS layout: PASS1 ----
#define L_STAGE   0        /* A buf0/buf1, B buf0/buf1: 4 x 8KB */
#define L_TR      32768    /* 64 x 66 x 8B transpose/exchange region */
#define L_CSTAT   66560    /* 8 x 64 x 8B col partials */
#define L_RRUN    70656    /* 64 x 8B row running */
#define L_CRUN    71168    /* 128 x 8B col running */
#define L_TOTAL   74240
// ---- LDS layout: PASS2 (stage 32K + X 32K + lse tables) ----
#define P2_LSER_D 65536
#define P2_LSEC_D 66560
#define P2_LSERF  67584
#define P2_LSECF  68096
#define P2_TOTAL  68608

__device__ __forceinline__ uint32 fkey(float f) {
    uint32 u = __float_as_uint(f);
    return (u & 0x80000000u) ? ~u : (u | 0x80000000u);
}
__device__ __forceinline__ float keyf(uint32 k) {
    uint32 u = (k & 0x80000000u) ? (k ^ 0x80000000u) : ~k;
    return __uint_as_float(u);
}
__device__ __forceinline__ i32x16 mfma_i8(i32x4 a, i32x4 b, i32x16 c) {
    return __builtin_amdgcn_mfma_i32_32x32x32_i8(a, b, c, 0, 0, 0);
}
__device__ __forceinline__ void load_lds16(const char* g, char* l) {
    __builtin_amdgcn_global_load_lds((__attribute__((address_space(1))) void*)(g),
                                     (__attribute__((address_space(3))) void*)(l), 16, 0, 0);
}
__device__ __forceinline__ u64 umax64(u64 a, u64 b) { return a > b ? a : b; }

__global__ void fill_sentinel(float* out, int nelem) {
    int i = blockIdx.x * 256 + threadIdx.x;
    if (i < nelem) out[i] = 12345.0f;
}

__global__ void init_packs(u64* __restrict__ rowpack, u64* __restrict__ colpack) {
    int idx = blockIdx.x * 256 + threadIdx.x;
    if (idx < BATCH * LDIM) { rowpack[idx] = 0ull; colpack[idx] = 0ull; }
}

// Quantize fp32 -> 4 exact base-128 signed digits of round(x*2^25).
__global__ __launch_bounds__(256) void quant_kernel(const float* __restrict__ f1,
                                                    const float* __restrict__ f2,
                                                    char* __restrict__ dig)
{
    int tid = blockIdx.x * 256 + threadIdx.x;
    int l31 = tid & 31;
    int kg  = (tid >> 5) & 1;
    int kc  = (tid >> 6) & 3;
    int rb  = (tid >> 8) & 1;
    int blk = (tid >> 9) & 63;
    int n   = (tid >> 15) & 7;
    int inp = tid >> 18;
    int row = blk * 64 + rb * 32 + l31;

    const float* src = (inp ? f2 : f1) + ((size_t)(n * LDIM + row)) * CDIM + kc * 32 + kg * 16;
    char* dstc = dig + (inp ? DIG2_OFF : DIG1_OFF)
               + (((size_t)n * 64 + blk) * 4 + kc) * 8192;
    int gpos = rb * 64 + kg * 32 + l31;

    float4 v0 = ((const float4*)src)[0];
    float4 v1 = ((const float4*)src)[1];
    float4 v2 = ((const float4*)src)[2];
    float4 v3 = ((const float4*)src)[3];
    float xs[16] = {v0.x,v0.y,v0.z,v0.w, v1.x,v1.y,v1.z,v1.w,
                    v2.x,v2.y,v2.z,v2.w, v3.x,v3.y,v3.z,v3.w};
    uint32 wds[4][4] = {{0,0,0,0},{0,0,0,0},{0,0,0,0},{0,0,0,0}};
#pragma unroll
    for (int e = 0; e < 16; e++) {
        int q = __float2int_rn(xs[e] * 33554432.0f);
        int d0 = (q + (1 << 20)) >> 21; q -= d0 << 21;
        int d1 = (q + (1 << 13)) >> 14; q -= d1 << 14;
        int d2 = (q + (1 << 6)) >> 7;   q -= d2 << 7;
        int sh = (e & 3) * 8;
        wds[0][e >> 2] |= (uint32)(d0 & 255) << sh;
        wds[1][e >> 2] |= (uint32)(d1 & 255) << sh;
        wds[2][e >> 2] |= (uint32)(d2 & 255) << sh;
        wds[3][e >> 2] |= (uint32)(q  & 255) << sh;
    }
#pragma unroll
    for (int p = 0; p < 4; p++) {
        *(int4*)(dstc + (size_t)(p * 128 + gpos) * 16) =
            make_int4(wds[p][0], wds[p][1], wds[p][2], wds[p][3]);
    }
}

// PASS 1: exact i8-digit GEMM -> per-128-tile (max, sum2exp) row/col partials
//         (log2 domain).
// PASS 2: recompute -> t01-filtered candidate keys, direct global atomicMax.
template <int PASS>
__global__ __launch_bounds__(512, 4) void gemm_kernel(
    const char* __restrict__ dig,
    float2* __restrict__ rowpart, float2* __restrict__ colpart,
    const double* __restrict__ lse_row, const double* __restrict__ lse_col,
    u64* __restrict__ rowpack, u64* __restrict__ colpack)
{
    __shared__ __align__(16) char sm[(PASS == 1) ? L_TOTAL : P2_TOTAL];
    double* lser_sh = (double*)(sm + P2_LSER_D);
    double* lsec_sh = (double*)(sm + P2_LSEC_D);
    float* lserf_sh = (float*)(sm + P2_LSERF);
    float* lsecf_sh = (float*)(sm + P2_LSECF);

    int wg = blockIdx.x;
    int swz = (wg & 7) * 1024 + (wg >> 3);    // one batch per XCD
    int n  = swz >> 10;
    int tM = (swz >> 5) & 31;
    int tN = swz & 31;

    const int t = threadIdx.x;
    const int lane = t & 63, w = t >> 6;
    const int bg = w & 1, rr = (w >> 1) & 1, cb = (w >> 2) & 1;
    const int pidx = w >> 1;
    const int l31 = lane & 31, kg = lane >> 5;

    if (PASS == 2) {
        if (t < 128) {
            double d = lse_row[(size_t)n * LDIM + tM * 128 + t];
            lser_sh[t] = d; lserf_sh[t] = (float)d;
        } else if (t < 256) {
            double d = lse_col[(size_t)n * LDIM + tN * 128 + (t - 128)];
            lsec_sh[t - 128] = d; lsecf_sh[t - 128] = (float)d;
        }
    }

    const i32x16 zero16 = {0,0,0,0,0,0,0,0,0,0,0,0,0,0,0,0};
    i32x16 accP = zero16, accQ = zero16;

    auto stage_step = [&](int s, int buf) {
        int q = s >> 2, kc = s & 3;
        int blkA = tM * 2 + (q >> 1);
        int blkB = tN * 2 + (q & 1);
        const char* gA = dig + DIG1_OFF + (((size_t)n * 64 + blkA) * 4 + kc) * 8192
                       + w * 1024 + lane * 16;
        const char* gB = dig + DIG2_OFF + (((size_t)n * 64 + blkB) * 4 + kc) * 8192
                       + w * 1024 + lane * 16;
        load_lds16(gA, sm + L_STAGE + buf * 8192 + w * 1024);
        load_lds16(gB, sm + L_STAGE + 16384 + buf * 8192 + w * 1024);
    };

    stage_step(0, 0);

    for (int s = 0; s < 16; ++s) {
        int q = s >> 2, kc = s & 3, buf = s & 1;
        int rq = q >> 1, cq = q & 1;
        __syncthreads();
        if (s < 15) stage_step(s + 1, (s + 1) & 1);

        const char* Ab = sm + L_STAGE + buf * 8192;
        const char* Bb = sm + L_STAGE + 16384 + buf * 8192;
        i32x4 aF[4], bF[4];
#pragma unroll
        for (int p = 0; p < 4; p++)
            aF[p] = *(const i32x4*)(Ab + (size_t)(p * 2048 + rr * 1024) + lane * 16);
#pragma unroll
        for (int p = 0; p < 4; p++)
            bF[p] = *(const i32x4*)(Bb + (size_t)(p * 2048 + cb * 1024) + lane * 16);

        if (bg == 0) {
            accP = mfma_i8(aF[0], bF[0], accP);                 // T0
            accQ = mfma_i8(aF[0], bF[3], accQ);                 // T3
            accQ = mfma_i8(aF[1], bF[2], accQ);
            accQ = mfma_i8(aF[2], bF[1], accQ);
            accQ = mfma_i8(aF[3], bF[0], accQ);
        } else {
            accP = mfma_i8(aF[0], bF[1], accP);                 // T1
            accP = mfma_i8(aF[1], bF[0], accP);
            accQ = mfma_i8(aF[0], bF[2], accQ);                 // T2
            accQ = mfma_i8(aF[1], bF[1], accQ);
            accQ = mfma_i8(aF[2], bF[0], accQ);
        }

        if (kc == 3) {
            // ---------- quadrant epilogue ----------
            char* X = sm + ((PASS == 1) ? L_TR : 32768) + pidx * 8192;
            if (bg == 0) {
#pragma unroll
                for (int er = 0; er < 8; er++) {
                    *(int*)(X + er * 256 + lane * 4)        = accP[er + 8];
                    *(int*)(X + 2048 + er * 256 + lane * 4) = accQ[er + 8];
                }
            } else {
#pragma unroll
                for (int er = 0; er < 8; er++) {
                    *(int*)(X + 4096 + er * 256 + lane * 4) = accP[er];
                    *(int*)(X + 6144 + er * 256 + lane * 4) = accQ[er];
                }
            }
            __syncthreads();
            int T0v[8], T1v[8], T2v[8], T3v[8];
            int r_base;
            if (bg == 0) {
                r_base = 0;
#pragma unroll
                for (int er = 0; er < 8; er++) {
                    T1v[er] = *(const int*)(X + 4096 + er * 256 + lane * 4);
                    T2v[er] = *(const int*)(X + 6144 + er * 256 + lane * 4);
                    T0v[er] = accP[er];
                    T3v[er] = accQ[er];
                }
            } else {
                r_base = 8;
#pragma unroll
                for (int er = 0; er < 8; er++) {
                    T0v[er] = *(const int*)(X + er * 256 + lane * 4);
                    T3v[er] = *(const int*)(X + 2048 + er * 256 + lane * 4);
                    T1v[er] = accP[er + 8];
                    T2v[er] = accQ[er + 8];
                }
            }
            accP = zero16; accQ = zero16;

            int qr[8];
#pragma unroll
            for (int er = 0; er < 8; er++) qr[er] = rr * 32 + CROW(r_base + er, kg);
            const int qc = cb * 32 + l31;

            if (PASS == 1) {
                __syncthreads();   // exchange reads done; TR region reusable
                double lam[8];
                float lamf[8];
#pragma unroll
                for (int er = 0; er < 8; er++) {
                    int t01 = T0v[er] * 128 + T1v[er];
                    int t23 = T2v[er] * 128 + T3v[er];
                    lam[er] = (double)t01 * C1L + (double)t23 * C2L;
                    lamf[er] = (float)lam[er];
                }
                const int contrib = rr * 4 + bg * 2 + kg;

                float cmax = lamf[0];
#pragma unroll
                for (int er = 1; er < 8; er++) cmax = fmaxf(cmax, lamf[er]);
                float cs = 0.f;
#pragma unroll
                for (int er = 0; er < 8; er++)
                    cs += exp2f((float)(lam[er] - (double)cmax));
                *(float2*)(sm + L_CSTAT + (contrib * 64 + qc) * 8) = make_float2(cmax, cs);
#pragma unroll
                for (int er = 0; er < 8; er++)
                    *(double*)(sm + L_TR + ((size_t)qr[er] * 66 + qc) * 8) = lam[er];
                __syncthreads();
                {
                    int gr = t >> 3, cofs = t & 7;
                    double v[8];
#pragma unroll
                    for (int j = 0; j < 8; j++)
                        v[j] = *(const double*)(sm + L_TR + ((size_t)gr * 66 + cofs + 8 * j) * 8);
                    double rmx = v[0];
#pragma unroll
                    for (int j = 1; j < 8; j++) rmx = fmax(rmx, v[j]);
                    rmx = fmax(rmx, __shfl_xor(rmx, 1));
                    rmx = fmax(rmx, __shfl_xor(rmx, 2));
                    rmx = fmax(rmx, __shfl_xor(rmx, 4));
                    float rmf = (float)rmx;
                    float rs = 0.f;
#pragma unroll
                    for (int j = 0; j < 8; j++)
                        rs += exp2f((float)(v[j] - (double)rmf));
                    rs += __shfl_xor(rs, 1);
                    rs += __shfl_xor(rs, 2);
                    rs += __shfl_xor(rs, 4);
                    if (cofs == 0) {
                        float2* RR = (float2*)(sm + L_RRUN);
                        if (cq == 0) RR[gr] = make_float2(rmf, rs);
                        else {
                            float2 p = RR[gr];
                            float F = fmaxf(rmf, p.x);
                            float FS = rs * exp2f(rmf - F) + p.y * exp2f(p.x - F);
                            rowpart[((size_t)n * LDIM + tM * 128 + rq * 64 + gr) * 32 + tN] =
                                make_float2(F, FS);
                        }
                    }
                }
                if (t < 64) {
                    float2 p0 = *(const float2*)(sm + L_CSTAT + t * 8);
                    float M = p0.x;
#pragma unroll
                    for (int i = 1; i < 8; i++)
                        M = fmaxf(M, ((const float2*)(sm + L_CSTAT + (i * 64 + t) * 8))->x);
                    float S = 0.f;
#pragma unroll
                    for (int i = 0; i < 8; i++) {
                        float2 p = *(const float2*)(sm + L_CSTAT + (i * 64 + t) * 8);
                        S += p.y * exp2f(p.x - M);
                    }
                    float2* CR = (float2*)(sm + L_CRUN);
                    if (rq == 0) CR[cq * 64 + t] = make_float2(M, S);
                    else {
                        float2 p = CR[cq * 64 + t];
                        float F = fmaxf(M, p.x);
                        float FS = S * exp2f(M - F) + p.y * exp2f(p.x - F);
                        colpart[((size_t)n * LDIM + tN * 128 + cq * 64 + t) * 32 + tM] =
                            make_float2(F, FS);
                    }
                }
            } else {
                // PASS 2: conservative t01 filter (margin 17 covers worst-case
                // |t23|*C2L*2 + f32 slop), exact keys only for candidates.
                const float two_c1f = (float)(2.0 * C1L);
                const int colt = cq * 64 + qc;
                const float scol = lsecf_sh[colt] + (float)LOG2_02 - 17.0f;
                const double lcd = lsec_sh[colt];
#pragma unroll
                for (int er = 0; er < 8; er++) {
                    int t01 = T0v[er] * 128 + T1v[er];
                    float lv = (float)t01 * two_c1f;
                    int rowt = rq * 64 + qr[er];
                    if (lv > lserf_sh[rowt] + scol) {
                        int t23 = T2v[er] * 128 + T3v[er];
                        double l2 = (double)t01 * C1L + (double)t23 * C2L;
                        float gf = (float)(2.0 * l2 - lser_sh[rowt] - lcd);
                        u64 key = ((u64)fkey(gf)) << 32;
                        atomicMax(&rowpack[(size_t)n * LDIM + tM * 128 + rowt],
                                  key | (uint32)(~(uint32)(tN * 128 + colt)));
                        atomicMax(&colpack[(size_t)n * LDIM + tN * 128 + colt],
                                  key | (uint32)(~(uint32)(tM * 128 + rowt)));
                    }
                }
            }
        }
    }
}

__global__ __launch_bounds__(256) void merge_kernel(
    const float2* __restrict__ rowpart, const float2* __restrict__ colpart,
    double* __restrict__ lse_row, double* __restrict__ lse_col)
{
    int idx = blockIdx.x * 256 + threadIdx.x;
    const float2* src = (idx < BATCH * LDIM) ? rowpart : colpart;
    double* dst = (idx < BATCH * LDIM) ? lse_row : lse_col;
    int i = idx & (BATCH * LDIM - 1);
    double M = -1e300;
#pragma unroll
    for (int j = 0; j < 32; j++) M = fmax(M, (double)src[(size_t)i * 32 + j].x);
    double S = 0.0;
#pragma unroll
    for (int j = 0; j < 32; j++) {
        float2 ms = src[(size_t)i * 32 + j];
        S += (double)ms.y * exp2((double)ms.x - M);
    }
    dst[i] = M + log2(S);
}

__global__ __launch_bounds__(256) void out_kernel(
    const float* __restrict__ f1, const float* __restrict__ f2,
    const u64* __restrict__ rowpack, const u64* __restrict__ colpack,
    float* __restrict__ out)
{
    int n = blockIdx.y;
    int l0 = blockIdx.x * 64;
    int t = threadIdx.x;
    __shared__ int s_sh[64];
    __shared__ int m_sh[64];
    __shared__ float tile[64][129];
    if (t < 64) {
        u64 rp = rowpack[(size_t)n * LDIM + l0 + t];
        uint32 skey = (uint32)(rp >> 32);
        uint32 s = (~(uint32)rp) & 4095u;
        u64 cp = colpack[(size_t)n * LDIM + s];
        double g2 = (double)keyf(skey);
        int match = (((uint32)(cp >> 32)) == skey) && (g2 > LOG2_02);
        s_sh[t] = (int)s;
        m_sh[t] = match;
    }
    __syncthreads();
#pragma unroll
    for (int i = 0; i < 32; i++) {
        int idx = i * 256 + t;
        int lloc = idx >> 7, ch = idx & 127;
        float v = f1[((size_t)n * LDIM + l0 + lloc) * CDIM + ch];
        if (m_sh[lloc]) v -= f2[((size_t)n * LDIM + s_sh[lloc]) * CDIM + ch];
        tile[lloc][ch] = v;
    }
    __syncthreads();
#pragma unroll
    for (int i = 0; i < 32; i++) {
        int ch = i * 4 + (t >> 6), lw = t & 63;
        out[((size_t)n * CDIM + ch) * LDIM + l0 + lw] = tile[lw][ch];
    }
}

extern "C" void kernel_launch(void* const* d_in, const int* in_sizes, int n_in,
                              void* d_out, int out_size, void* d_ws, size_t ws_size,
                              hipStream_t stream)
{
    const float* f1 = (const float*)d_in[0];
    const float* f2 = (const float*)d_in[1];
    float* out = (float*)d_out;
    char* ws = (char*)d_ws;
    char* dig = ws;

    if (ws_size < WS_NEEDED) {
        fill_sentinel<<<(out_size + 255) / 256, 256, 0, stream>>>(out, out_size);
        return;
    }

    float2* rowpart = (float2*)(ws + ROWPART_OFF);
    float2* colpart = (float2*)(ws + COLPART_OFF);
    double* lse_row = (double*)(ws + LSER_OFF);
    double* lse_col = (double*)(ws + LSEC_OFF);
    u64* rowpack = (u64*)(ws + RPACK_OFF);
    u64* colpack = (u64*)(ws + CPACK_OFF);

    quant_kernel<<<dim3(2048), dim3(256), 0, stream>>>(f1, f2, dig);
    init_packs<<<dim3(128), dim3(256), 0, stream>>>(rowpack, colpack);
    gemm_kernel<1><<<dim3(8192), dim3(512), 0, stream>>>(
        dig, rowpart, colpart, lse_row, lse_col, rowpack, colpack);
    merge_kernel<<<dim3(256), dim3(256), 0, stream>>>(rowpart, colpart, lse_row, lse_col);
    gemm_kernel<2><<<dim3(8192), dim3(512), 0, stream>>>(
        dig, rowpart, colpart, lse_row, lse_col, rowpack, colpack);
    out_kernel<<<dim3(LDIM / 64, BATCH), dim3(256), 0, stream>>>(
        f1, f2, rowpack, colpack, out);
}

// Round 7
// 518.122 us; speedup vs baseline: 9.7632x; 1.4021x over previous
//
#include <hip/hip_runtime.h>
#include <stdint.h>

typedef unsigned int uint32;
typedef unsigned long long u64;

#define BATCH 8
#define LDIM 4096
#define CDIM 128

typedef __attribute__((ext_vector_type(4))) int i32x4;
typedef __attribute__((ext_vector_type(16))) int i32x16;

// ---- workspace layout (bytes) ----
#define DIG1_OFF    0ull          /* i8 digits f1, LDS-order: 16 MB */
#define DIG2_OFF    16777216ull   /* i8 digits f2 */
#define ROWPART_OFF 33554432ull   /* float2 [8][4096][32] = 8 MB */
#define COLPART_OFF 41943040ull   /* float2 [8][4096][32] = 8 MB */
#define LSER_OFF    50331648ull   /* double [8][4096] */
#define LSEC_OFF    50593792ull
#define RPACK_OFF   50855936ull   /* u64 [8][4096] */
#define CPACK_OFF   51118080ull
#define WS_NEEDED   51380224ull

// lam2 = log2(e) * 10 * (t01*2^-15 + t23*2^-29)  (log2-domain logits)
#define C1L (3.0517578125e-04 * 1.4426950408889634)
#define C2L (1.862645149230957e-08 * 1.4426950408889634)
#define LOG2_02 (-2.3219280948873623)   /* log2(0.2) */

#define CROW(r, kgv) (((r)&3) + 8*((r)>>2) + 4*(kgv))

__device__ __forceinline__ uint32 fkey(float f) {
    uint32 u = __float_as_uint(f);
    return (u & 0x80000000u) ? ~u : (u | 0x80000000u);
}
__device__ __forceinline__ float keyf(uint32 k) {
    uint32 u = (k & 0x80000000u) ? (k ^ 0x80000000u) : ~k;
    return __uint_as_float(u);
}
__device__ __forceinline__ i32x16 mfma_i8(i32x4 a, i32x4 b, i32x16 c) {
    return __builtin_amdgcn_mfma_i32_32x32x32_i8(a, b, c, 0, 0, 0);
}
__device__ __forceinline__ void load_lds16(const char* g, char* l) {
    __builtin_amdgcn_global_load_lds((__attribute__((address_space(1))) void*)(g),
                                     (__attribute__((address_space(3))) void*)(l), 16, 0, 0);
}
__device__ __forceinline__ u64 umax64(u64 a, u64 b) { return a > b ? a : b; }

__global__ void fill_sentinel(float* out, int nelem) {
    int i = blockIdx.x * 256 + threadIdx.x;
    if (i < nelem) out[i] = 12345.0f;
}

__global__ void init_packs(u64* __restrict__ rowpack, u64* __restrict__ colpack) {
    int idx = blockIdx.x * 256 + threadIdx.x;
    if (idx < BATCH * LDIM) { rowpack[idx] = 0ull; colpack[idx] = 0ull; }
}

// Quantize fp32 -> 4 exact base-128 signed digits of round(x*2^25).
__global__ __launch_bounds__(256) void quant_kernel(const float* __restrict__ f1,
                                                    const float* __restrict__ f2,
                                                    char* __restrict__ dig)
{
    int tid = blockIdx.x * 256 + threadIdx.x;
    int l31 = tid & 31;
    int kg  = (tid >> 5) & 1;
    int kc  = (tid >> 6) & 3;
    int rb  = (tid >> 8) & 1;
    int blk = (tid >> 9) & 63;
    int n   = (tid >> 15) & 7;
    int inp = tid >> 18;
    int row = blk * 64 + rb * 32 + l31;

    const float* src = (inp ? f2 : f1) + ((size_t)(n * LDIM + row)) * CDIM + kc * 32 + kg * 16;
    char* dstc = dig + (inp ? DIG2_OFF : DIG1_OFF)
               + (((size_t)n * 64 + blk) * 4 + kc) * 8192;
    int gpos = rb * 64 + kg * 32 + l31;

    float4 v0 = ((const float4*)src)[0];
    float4 v1 = ((const float4*)src)[1];
    float4 v2 = ((const float4*)src)[2];
    float4 v3 = ((const float4*)src)[3];
    float xs[16] = {v0.x,v0.y,v0.z,v0.w, v1.x,v1.y,v1.z,v1.w,
                    v2.x,v2.y,v2.z,v2.w, v3.x,v3.y,v3.z,v3.w};
    uint32 wds[4][4] = {{0,0,0,0},{0,0,0,0},{0,0,0,0},{0,0,0,0}};
#pragma unroll
    for (int e = 0; e < 16; e++) {
        int q = __float2int_rn(xs[e] * 33554432.0f);
        int d0 = (q + (1 << 20)) >> 21; q -= d0 << 21;
        int d1 = (q + (1 << 13)) >> 14; q -= d1 << 14;
        int d2 = (q + (1 << 6)) >> 7;   q -= d2 << 7;
        int sh = (e & 3) * 8;
        wds[0][e >> 2] |= (uint32)(d0 & 255) << sh;
        wds[1][e >> 2] |= (uint32)(d1 & 255) << sh;
        wds[2][e >> 2] |= (uint32)(d2 & 255) << sh;
        wds[3][e >> 2] |= (uint32)(q  & 255) << sh;
    }
#pragma unroll
    for (int p = 0; p < 4; p++) {
        *(int4*)(dstc + (size_t)(p * 128 + gpos) * 16) =
            make_int4(wds[p][0], wds[p][1], wds[p][2], wds[p][3]);
    }
}

// 8 waves = (wr in {0,1}) x (wc in {0..3}); each wave owns 64x32 output
// (M=2 subtiles of 32x32) with ALL 4 digit banks -> no exchange, epilogue
// once per block. 4 kc-steps of K=32, dbuf global_load_lds staging.
template <int PASS>
__global__ __launch_bounds__(512, 2) void gemm_kernel(
    const char* __restrict__ dig,
    float2* __restrict__ rowpart, float2* __restrict__ colpart,
    const double* __restrict__ lse_row, const double* __restrict__ lse_col,
    u64* __restrict__ rowpack, u64* __restrict__ colpack)
{
    __shared__ __align__(16) char smp[(PASS == 1) ? 74240 : 68608];
    // PASS1: stage 64K (reused post-loop as trf f32[128][129] = 66048)
    //        rstat f2[4][128] @66048, cpart f2[4][128] @70144
    // PASS2: stage 64K + lse tables @65536 (3072B)

    int wg = blockIdx.x;
    int swz = (wg & 7) * 1024 + (wg >> 3);    // one batch per XCD
    int n  = swz >> 10;
    int tM = (swz >> 5) & 31;
    int tN = swz & 31;

    const int t = threadIdx.x;
    const int lane = t & 63, w = t >> 6;
    const int wr = w >> 2, wc = w & 3;
    const int l31 = lane & 31, kg = lane >> 5;

    double* lserd = (double*)(smp + 65536);
    double* lsecd = (double*)(smp + 66560);
    float*  lserf = (float*)(smp + 67584);
    float*  lsecf = (float*)(smp + 68096);
    if (PASS == 2) {
        if (t < 128) {
            double d = lse_row[(size_t)n * LDIM + tM * 128 + t];
            lserd[t] = d; lserf[t] = (float)d;
        } else if (t < 256) {
            int c = t - 128;
            double d = lse_col[(size_t)n * LDIM + tN * 128 + c];
            lsecd[c] = d; lsecf[c] = (float)d;
        }
    }

    const i32x16 zero16 = {0,0,0,0,0,0,0,0,0,0,0,0,0,0,0,0};
    i32x16 acc[2][4];
#pragma unroll
    for (int sm = 0; sm < 2; sm++)
#pragma unroll
        for (int k = 0; k < 4; k++) acc[sm][k] = zero16;

    auto stage_step = [&](int kc, int buf) {
#pragma unroll
        for (int i = 0; i < 4; i++) {
            int blk = (i < 2) ? (tM * 2 + i) : (tN * 2 + (i - 2));
            const char* src = dig + ((i < 2) ? DIG1_OFF : DIG2_OFF)
                            + (((size_t)n * 64 + blk) * 4 + kc) * 8192 + t * 16;
            load_lds16(src, smp + buf * 32768 + i * 8192 + t * 16);
        }
    };

    stage_step(0, 0);
    for (int kc = 0; kc < 4; kc++) {
        int buf = kc & 1;
        __syncthreads();
        if (kc < 3) stage_step(kc + 1, buf ^ 1);
        const char* Ab = smp + buf * 32768 + wr * 8192;
        const char* Bb = smp + buf * 32768 + 16384 + (wc >> 1) * 8192 + (wc & 1) * 1024;
        i32x4 aF[2][4], bF[4];
#pragma unroll
        for (int p = 0; p < 4; p++)
            bF[p] = *(const i32x4*)(Bb + p * 2048 + lane * 16);
#pragma unroll
        for (int sm = 0; sm < 2; sm++)
#pragma unroll
            for (int p = 0; p < 4; p++)
                aF[sm][p] = *(const i32x4*)(Ab + p * 2048 + sm * 1024 + lane * 16);
#pragma unroll
        for (int sm = 0; sm < 2; sm++) {
            acc[sm][0] = mfma_i8(aF[sm][0], bF[0], acc[sm][0]);   // T0
            acc[sm][1] = mfma_i8(aF[sm][0], bF[1], acc[sm][1]);   // T1
            acc[sm][1] = mfma_i8(aF[sm][1], bF[0], acc[sm][1]);
            acc[sm][2] = mfma_i8(aF[sm][0], bF[2], acc[sm][2]);   // T2
            acc[sm][2] = mfma_i8(aF[sm][1], bF[1], acc[sm][2]);
            acc[sm][2] = mfma_i8(aF[sm][2], bF[0], acc[sm][2]);
            acc[sm][3] = mfma_i8(aF[sm][0], bF[3], acc[sm][3]);   // T3
            acc[sm][3] = mfma_i8(aF[sm][1], bF[2], acc[sm][3]);
            acc[sm][3] = mfma_i8(aF[sm][2], bF[1], acc[sm][3]);
            acc[sm][3] = mfma_i8(aF[sm][3], bF[0], acc[sm][3]);
        }
    }

    const int col = wc * 32 + l31;

    if (PASS == 1) {
        float* trf = (float*)smp;                       // [128][129] (overlaps stage)
        float2* rstat = (float2*)(smp + 66048);         // [4][128]
        float2* cpart = (float2*)(smp + 70144);         // [4][128]

        __syncthreads();   // all frag reads done; stage region reusable

        float lamf[2][16];
#pragma unroll
        for (int sm = 0; sm < 2; sm++)
#pragma unroll
            for (int r = 0; r < 16; r++) {
                int t01 = acc[sm][0][r] * 128 + acc[sm][1][r];
                int t23 = acc[sm][2][r] * 128 + acc[sm][3][r];
                float lf = (float)((double)t01 * C1L + (double)t23 * C2L);
                lamf[sm][r] = lf;
                int row = wr * 64 + sm * 32 + CROW(r, kg);
                trf[row * 129 + col] = lf;
            }
        float cm = lamf[0][0];
#pragma unroll
        for (int sm = 0; sm < 2; sm++)
#pragma unroll
            for (int r = 0; r < 16; r++) cm = fmaxf(cm, lamf[sm][r]);
        float cs = 0.f;
#pragma unroll
        for (int sm = 0; sm < 2; sm++)
#pragma unroll
            for (int r = 0; r < 16; r++) cs += exp2f(lamf[sm][r] - cm);
        cpart[(wr * 2 + kg) * 128 + col] = make_float2(cm, cs);
        __syncthreads();

        {   // row stats: thread -> (row = t&127, seg = t>>7), 32 cols each
            int row = t & 127, seg = t >> 7;
            const float* rp = trf + row * 129 + seg * 32;
            float v[32];
#pragma unroll
            for (int j = 0; j < 32; j++) v[j] = rp[j];
            float rm = v[0];
#pragma unroll
            for (int j = 1; j < 32; j++) rm = fmaxf(rm, v[j]);
            float rs = 0.f;
#pragma unroll
            for (int j = 0; j < 32; j++) rs += exp2f(v[j] - rm);
            rstat[seg * 128 + row] = make_float2(rm, rs);
        }
        __syncthreads();
        if (t < 128) {
            float2 a = rstat[t], b = rstat[128 + t], c = rstat[256 + t], d = rstat[384 + t];
            float M = fmaxf(fmaxf(a.x, b.x), fmaxf(c.x, d.x));
            float S = a.y * exp2f(a.x - M) + b.y * exp2f(b.x - M)
                    + c.y * exp2f(c.x - M) + d.y * exp2f(d.x - M);
            rowpart[((size_t)n * LDIM + tM * 128 + t) * 32 + tN] = make_float2(M, S);
        } else if (t < 256) {
            int c0 = t - 128;
            float2 a = cpart[c0], b = cpart[128 + c0], c = cpart[256 + c0], d = cpart[384 + c0];
            float M = fmaxf(fmaxf(a.x, b.x), fmaxf(c.x, d.x));
            float S = a.y * exp2f(a.x - M) + b.y * exp2f(b.x - M)
                    + c.y * exp2f(c.x - M) + d.y * exp2f(d.x - M);
            colpart[((size_t)n * LDIM + tN * 128 + c0) * 32 + tM] = make_float2(M, S);
        }
    } else {
        // PASS 2: in-register t01 filter (margin 17 conservative), exact keys
        // for rare candidates, direct global atomicMax.
        const float two_c1f = (float)(2.0 * C1L);
        const float scol = lsecf[col] + (float)LOG2_02 - 17.0f;
        const double lcd = lsecd[col];
#pragma unroll
        for (int sm = 0; sm < 2; sm++)
#pragma unroll
            for (int r = 0; r < 16; r++) {
                int row = wr * 64 + sm * 32 + CROW(r, kg);
                int t01 = acc[sm][0][r] * 128 + acc[sm][1][r];
                float lv = (float)t01 * two_c1f;
                if (lv > lserf[row] + scol) {
                    int t23 = acc[sm][2][r] * 128 + acc[sm][3][r];
                    double l2 = (double)t01 * C1L + (double)t23 * C2L;
                    float gf = (float)(2.0 * l2 - lserd[row] - lcd);
                    u64 key = ((u64)fkey(gf)) << 32;
                    atomicMax(&rowpack[(size_t)n * LDIM + tM * 128 + row],
                              key | (uint32)(~(uint32)(tN * 128 + col)));
                    atomicMax(&colpack[(size_t)n * LDIM + tN * 128 + col],
                              key | (uint32)(~(uint32)(tM * 128 + row)));
                }
            }
    }
}

__global__ __launch_bounds__(256) void merge_kernel(
    const float2* __restrict__ rowpart, const float2* __restrict__ colpart,
    double* __restrict__ lse_row, double* __restrict__ lse_col)
{
    int idx = blockIdx.x * 256 + threadIdx.x;
    const float2* src = (idx < BATCH * LDIM) ? rowpart : colpart;
    double* dst = (idx < BATCH * LDIM) ? lse_row : lse_col;
    int i = idx & (BATCH * LDIM - 1);
    double M = -1e300;
#pragma unroll
    for (int j = 0; j < 32; j++) M = fmax(M, (double)src[(size_t)i * 32 + j].x);
    double S = 0.0;
#pragma unroll
    for (int j = 0; j < 32; j++) {
        float2 ms = src[(size_t)i * 32 + j];
        S += (double)ms.y * exp2((double)ms.x - M);
    }
    dst[i] = M + log2(S);
}

__global__ __launch_bounds__(256) void out_kernel(
    const float* __restrict__ f1, const float* __restrict__ f2,
    const u64* __restrict__ rowpack, const u64* __restrict__ colpack,
    float* __restrict__ out)
{
    int n = blockIdx.y;
    int l0 = blockIdx.x * 64;
    int t = threadIdx.x;
    __shared__ int s_sh[64];
    __shared__ int m_sh[64];
    __shared__ float tile[64][129];
    if (t < 64) {
        u64 rp = rowpack[(size_t)n * LDIM + l0 + t];
        uint32 skey = (uint32)(rp >> 32);
        uint32 s = (~(uint32)rp) & 4095u;
        u64 cp = colpack[(size_t)n * LDIM + s];
        double g2 = (double)keyf(skey);
        int match = (((uint32)(cp >> 32)) == skey) && (g2 > LOG2_02);
        s_sh[t] = (int)s;
        m_sh[t] = match;
    }
    __syncthreads();
#pragma unroll
    for (int i = 0; i < 32; i++) {
        int idx = i * 256 + t;
        int lloc = idx >> 7, ch = idx & 127;
        float v = f1[((size_t)n * LDIM + l0 + lloc) * CDIM + ch];
        if (m_sh[lloc]) v -= f2[((size_t)n * LDIM + s_sh[lloc]) * CDIM + ch];
        tile[lloc][ch] = v;
    }
    __syncthreads();
#pragma unroll
    for (int i = 0; i < 32; i++) {
        int ch = i * 4 + (t >> 6), lw = t & 63;
        out[((size_t)n * CDIM + ch) * LDIM + l0 + lw] = tile[lw][ch];
    }
}

extern "C" void kernel_launch(void* const* d_in, const int* in_sizes, int n_in,
                              void* d_out, int out_size, void* d_ws, size_t ws_size,
                              hipStream_t stream)
{
    const float* f1 = (const float*)d_in[0];
    const float* f2 = (const float*)d_in[1];
    float* out = (float*)d_out;
    char* ws = (char*)d_ws;
    char* dig = ws;

    if (ws_size < WS_NEEDED) {
        fill_sentinel<<<(out_size + 255) / 256, 256, 0, stream>>>(out, out_size);
        return;
    }

    float2* rowpart = (float2*)(ws + ROWPART_OFF);
    float2* colpart = (float2*)(ws + COLPART_OFF);
    double* lse_row = (double*)(ws + LSER_OFF);
    double* lse_col = (double*)(ws + LSEC_OFF);
    u64* rowpack = (u64*)(ws + RPACK_OFF);
    u64* colpack = (u64*)(ws + CPACK_OFF);

    quant_kernel<<<dim3(2048), dim3(256), 0, stream>>>(f1, f2, dig);
    init_packs<<<dim3(128), dim3(256), 0, stream>>>(rowpack, colpack);
    gemm_kernel<1><<<dim3(8192), dim3(512), 0, stream>>>(
        dig, rowpart, colpart, lse_row, lse_col, rowpack, colpack);
    merge_kernel<<<dim3(256), dim3(256), 0, stream>>>(rowpart, colpart, lse_row, lse_col);
    gemm_kernel<2><<<dim3(8192), dim3(512), 0, stream>>>(
        dig, rowpart, colpart, lse_row, lse_col, rowpack, colpack);
    out_kernel<<<dim3(LDIM / 64, BATCH), dim3(256), 0, stream>>>(
        f1, f2, rowpack, colpack, out);
}